// Round 1
// baseline (4063.329 us; speedup 1.0000x reference)
//
#include <hip/hip_runtime.h>
#include <math.h>

#define N_NODES 100000
#define N_EDGES 600000
#define D 128
#define HEADS 8
#define DH 16
#define REL 9
#define NG 64

// ---------------------------------------------------------------- utilities
__device__ __forceinline__ int lbound(const int* __restrict__ a, int n, int key) {
    int lo = 0, hi = n;
    while (lo < hi) { int mid = (lo + hi) >> 1; if (a[mid] < key) lo = mid + 1; else hi = mid; }
    return lo;
}

// ------------------------------------------------------------ edge sorting
__global__ void hist_kernel(const int* __restrict__ dst, int* __restrict__ cnt) {
    int e = blockIdx.x * 256 + threadIdx.x;
    if (e < N_EDGES) atomicAdd(&cnt[dst[e]], 1);
}

__global__ void scan1_kernel(const int* __restrict__ cnt, int* __restrict__ excl,
                             int* __restrict__ bsum, int n) {
    __shared__ int s[1024];
    int tid = threadIdx.x;
    int i = blockIdx.x * 1024 + tid;
    int v = (i < n) ? cnt[i] : 0;
    s[tid] = v;
    __syncthreads();
    for (int off = 1; off < 1024; off <<= 1) {
        int t = (tid >= off) ? s[tid - off] : 0;
        __syncthreads();
        s[tid] += t;
        __syncthreads();
    }
    if (i < n) excl[i] = s[tid] - v;          // exclusive within block
    if (tid == 1023) bsum[blockIdx.x] = s[1023];
}

__global__ void scan2_kernel(int* __restrict__ bsum, int nb) {
    __shared__ int s[128];
    int tid = threadIdx.x;
    int v = (tid < nb) ? bsum[tid] : 0;
    s[tid] = v;
    __syncthreads();
    for (int off = 1; off < 128; off <<= 1) {
        int t = (tid >= off) ? s[tid - off] : 0;
        __syncthreads();
        s[tid] += t;
        __syncthreads();
    }
    if (tid < nb) bsum[tid] = s[tid] - v;     // exclusive block offsets
}

__global__ void scan3_kernel(int* __restrict__ excl, const int* __restrict__ bsum, int n) {
    int i = blockIdx.x * 1024 + threadIdx.x;
    if (i < n) excl[i] += bsum[blockIdx.x];
}

__global__ void scatter_kernel(const int* __restrict__ src, const int* __restrict__ dst,
                               const int* __restrict__ ety, const int* __restrict__ estart,
                               int* __restrict__ cur, int* __restrict__ ssrc,
                               int* __restrict__ setp) {
    int e = blockIdx.x * 256 + threadIdx.x;
    if (e < N_EDGES) {
        int d = dst[e];
        int pos = estart[d] + atomicAdd(&cur[d], 1);
        ssrc[pos] = src[e];
        setp[pos] = ety[e];
    }
}

// ------------------------------------------------------------- graph norm
// one block per graph; seg is sorted so graph g is a contiguous node range.
__global__ __launch_bounds__(512)
void graphnorm_kernel(const float* __restrict__ x, const int* __restrict__ seg,
                      const float* __restrict__ w, const float* __restrict__ b,
                      const float* __restrict__ ms, float* __restrict__ out) {
    int g = blockIdx.x;
    int lo = lbound(seg, N_NODES, g);
    int hi = lbound(seg, N_NODES, g + 1);
    int cntn = hi - lo;
    if (cntn == 0) return;
    int ch = threadIdx.x & 127;
    int rr = threadIdx.x >> 7;                 // 0..3
    __shared__ float red[4][128];
    __shared__ float meansh[128];
    __shared__ float rstd[128];
    float s = 0.f;
    for (int n = lo + rr; n < hi; n += 4) s += x[(size_t)n * D + ch];
    red[rr][ch] = s;
    __syncthreads();
    if (rr == 0) {
        float m = (red[0][ch] + red[1][ch] + red[2][ch] + red[3][ch]) / (float)cntn;
        meansh[ch] = m * ms[ch];               // mean * ms (the subtracted quantity)
    }
    __syncthreads();
    float mm = meansh[ch];
    float v = 0.f;
    for (int n = lo + rr; n < hi; n += 4) {
        float d0 = x[(size_t)n * D + ch] - mm;
        v += d0 * d0;
    }
    __syncthreads();
    red[rr][ch] = v;
    __syncthreads();
    if (rr == 0) {
        float var = (red[0][ch] + red[1][ch] + red[2][ch] + red[3][ch]) / (float)cntn;
        rstd[ch] = rsqrtf(var + 1e-6f);
    }
    __syncthreads();
    float wc = w[ch], bc = b[ch], rs = rstd[ch];
    for (int n = lo + rr; n < hi; n += 4) {
        float sub = x[(size_t)n * D + ch] - mm;
        out[(size_t)n * D + ch] = wc * sub * rs + bc;
    }
}

// ----------------------------------------------------- W = coeff x basis (transposed)
// Wt[i][r*128+o] = sum_b coeff[r,b] * basis[b,i,o]
__global__ void build_wt_kernel(const float* __restrict__ coeff, const float* __restrict__ basis,
                                float* __restrict__ wt) {
    int t = blockIdx.x * 256 + threadIdx.x;
    if (t >= REL * D * D) return;
    int o = t & 127;
    int i = (t >> 7) & 127;
    int r = t >> 14;
    float s = 0.f;
#pragma unroll
    for (int bb = 0; bb < REL; ++bb)
        s += coeff[r * REL + bb] * basis[((size_t)bb * D + i) * D + o];
    wt[(size_t)i * (REL * D) + r * D + o] = s;
}

// ------------------------------------------------------------- fp32 GEMM
// C[M x *] tile 64 rows x 128 cols, block 256 threads, thread tile 4x8.
// W element = W[k*ldw + wcol0 + col0 + c]; C element = C[row*ldc + col0 + c].
template<int K, bool BIAS, bool RELU>
__global__ __launch_bounds__(256)
void gemm_kernel(const float* __restrict__ A, const float* __restrict__ W, int ldw, int wcol0,
                 const float* __restrict__ bias, float* __restrict__ C, int ldc, int M) {
    __shared__ float As[32][68];    // [k][r], padded for 16B alignment
    __shared__ float Ws[32][128];   // [k][c]
    const int tid  = threadIdx.x;
    const int row0 = blockIdx.x * 64;
    const int col0 = blockIdx.y * 128;
    const int tr = (tid & 15) * 4;
    const int tc = (tid >> 4) * 8;
    const int sa_r = tid >> 2;          // 0..63
    const int sa_k = (tid & 3) * 8;     // 0,8,16,24
    const int sw_c = (tid & 31) * 4;    // 0..124
    const int sw_k = tid >> 5;          // 0..7

    float acc[4][8];
#pragma unroll
    for (int i = 0; i < 4; ++i)
#pragma unroll
        for (int j = 0; j < 8; ++j) acc[i][j] = 0.f;

    for (int kc = 0; kc < K; kc += 32) {
        {   // stage A (transposed)
            const int gr = row0 + sa_r;
            float4 v0 = make_float4(0.f, 0.f, 0.f, 0.f), v1 = v0;
            if (gr < M) {
                const float* ap = A + (size_t)gr * K + kc + sa_k;
                v0 = *(const float4*)(ap);
                v1 = *(const float4*)(ap + 4);
            }
            As[sa_k + 0][sa_r] = v0.x; As[sa_k + 1][sa_r] = v0.y;
            As[sa_k + 2][sa_r] = v0.z; As[sa_k + 3][sa_r] = v0.w;
            As[sa_k + 4][sa_r] = v1.x; As[sa_k + 5][sa_r] = v1.y;
            As[sa_k + 6][sa_r] = v1.z; As[sa_k + 7][sa_r] = v1.w;
        }
        {   // stage W
            const float* wp = W + (size_t)(kc + sw_k) * ldw + wcol0 + col0 + sw_c;
#pragma unroll
            for (int p = 0; p < 4; ++p)
                *(float4*)&Ws[sw_k + p * 8][sw_c] = *(const float4*)(wp + (size_t)p * 8 * ldw);
        }
        __syncthreads();
#pragma unroll
        for (int k = 0; k < 32; ++k) {
            float4 a  = *(const float4*)&As[k][tr];
            float4 w0 = *(const float4*)&Ws[k][tc];
            float4 w1 = *(const float4*)&Ws[k][tc + 4];
            float ar[4] = {a.x, a.y, a.z, a.w};
            float wr[8] = {w0.x, w0.y, w0.z, w0.w, w1.x, w1.y, w1.z, w1.w};
#pragma unroll
            for (int i = 0; i < 4; ++i)
#pragma unroll
                for (int j = 0; j < 8; ++j)
                    acc[i][j] = fmaf(ar[i], wr[j], acc[i][j]);
        }
        __syncthreads();
    }
#pragma unroll
    for (int i = 0; i < 4; ++i) {
        int gr = row0 + tr + i;
        if (gr < M) {
            float out[8];
#pragma unroll
            for (int j = 0; j < 8; ++j) {
                float v = acc[i][j];
                if (BIAS) v += bias[col0 + tc + j];
                if (RELU) v = fmaxf(v, 0.f);
                out[j] = v;
            }
            float4* cp = (float4*)(C + (size_t)gr * ldc + col0 + tc);
            cp[0] = make_float4(out[0], out[1], out[2], out[3]);
            cp[1] = make_float4(out[4], out[5], out[6], out[7]);
        }
    }
}

// ------------------------------------------- relconv message aggregation
// one wave per destination node; edges sorted by dst. P[n] (+)= sum X[src, et]; relu on last pass.
__global__ __launch_bounds__(256)
void segsum_kernel(const float* __restrict__ X, int ldx, const int* __restrict__ ssrc,
                   const int* __restrict__ setp, const int* __restrict__ estart,
                   const int* __restrict__ ecnt, float* __restrict__ P,
                   int gbase, int gcnt, int dorelu) {
    int gw = (blockIdx.x * 256 + threadIdx.x) >> 6;
    if (gw >= N_NODES) return;
    int lane = threadIdx.x & 63;
    int e0 = estart[gw], e1 = e0 + ecnt[gw];
    float2 acc = make_float2(0.f, 0.f);
    for (int e = e0; e < e1; ++e) {
        unsigned r = (unsigned)(setp[e] - gbase);
        if (r < (unsigned)gcnt) {
            float2 xv = *(const float2*)&X[(size_t)ssrc[e] * ldx + r * 128 + lane * 2];
            acc.x += xv.x; acc.y += xv.y;
        }
    }
    float2* pp = (float2*)&P[(size_t)gw * D + lane * 2];
    float2 pv = *pp;
    pv.x += acc.x; pv.y += acc.y;
    if (dorelu) { pv.x = fmaxf(pv.x, 0.f); pv.y = fmaxf(pv.y, 0.f); }
    *pp = pv;
}

// --------------------------------------------------------------- attention
// one wave per dst node; per-head dot via 8-lane shfl reduce; exp(clip); normalize in-wave.
__global__ __launch_bounds__(256)
void attn_kernel(const float* __restrict__ Q, const float* __restrict__ K,
                 const float* __restrict__ V, const int* __restrict__ ssrc,
                 const int* __restrict__ estart, const int* __restrict__ ecnt,
                 float* __restrict__ attn) {
    int n = (blockIdx.x * 256 + threadIdx.x) >> 6;
    if (n >= N_NODES) return;
    int lane = threadIdx.x & 63;   // channels 2*lane, 2*lane+1 ; head = lane>>3
    float2 q = ((const float2*)&Q[(size_t)n * D])[lane];
    int e0 = estart[n], e1 = e0 + ecnt[n];
    float2 wv = make_float2(0.f, 0.f);
    float z = 0.f;
    for (int e = e0; e < e1; ++e) {
        int s = ssrc[e];
        float2 kv = ((const float2*)&K[(size_t)s * D])[lane];
        float d = kv.x * q.x + kv.y * q.y;
        d += __shfl_xor(d, 1);
        d += __shfl_xor(d, 2);
        d += __shfl_xor(d, 4);
        float sc = d * 0.25f;                       // / sqrt(16)
        sc = fminf(fmaxf(sc, -10.f), 10.f);
        sc = expf(sc);
        float2 vv = ((const float2*)&V[(size_t)s * D])[lane];
        wv.x += sc * vv.x; wv.y += sc * vv.y;
        z += sc;
    }
    float inv = 1.f / (z + 1e-6f);
    ((float2*)&attn[(size_t)n * D])[lane] = make_float2(wv.x * inv, wv.y * inv);
}

// --------------------------------------------------------------- layernorm
__global__ __launch_bounds__(256)
void ln_kernel(const float* __restrict__ x, const float* __restrict__ g,
               const float* __restrict__ b, float* __restrict__ out) {
    int n = (blockIdx.x * 256 + threadIdx.x) >> 6;
    if (n >= N_NODES) return;
    int lane = threadIdx.x & 63;
    float2 v = ((const float2*)&x[(size_t)n * D])[lane];
    float s = v.x + v.y;
#pragma unroll
    for (int off = 1; off < 64; off <<= 1) s += __shfl_xor(s, off);
    float mu = s * (1.f / 128.f);
    float dx = v.x - mu, dy = v.y - mu;
    float vs = dx * dx + dy * dy;
#pragma unroll
    for (int off = 1; off < 64; off <<= 1) vs += __shfl_xor(vs, off);
    float rstd = rsqrtf(vs * (1.f / 128.f) + 1e-5f);
    float2 gg = ((const float2*)g)[lane];
    float2 bb = ((const float2*)b)[lane];
    ((float2*)&out[(size_t)n * D])[lane] =
        make_float2(gg.x * dx * rstd + bb.x, gg.y * dy * rstd + bb.y);
}

// ------------------------------------------------------------------ launch
extern "C" void kernel_launch(void* const* d_in, const int* in_sizes, int n_in,
                              void* d_out, int out_size, void* d_ws, size_t ws_size,
                              hipStream_t stream) {
    (void)in_sizes; (void)n_in; (void)out_size;
    const float* h     = (const float*)d_in[0];
    const int*   src   = (const int*)d_in[1];
    const int*   dst   = (const int*)d_in[2];
    const int*   ety   = (const int*)d_in[3];
    const int*   seg   = (const int*)d_in[4];
    const float* coeffs[3] = {(const float*)d_in[6],  (const float*)d_in[10], (const float*)d_in[14]};
    const float* bases [3] = {(const float*)d_in[7],  (const float*)d_in[11], (const float*)d_in[15]};
    const float* loops [3] = {(const float*)d_in[8],  (const float*)d_in[12], (const float*)d_in[16]};
    const float* pbias [3] = {(const float*)d_in[9],  (const float*)d_in[13], (const float*)d_in[17]};
    const float* o_w   = (const float*)d_in[18];
    const float* o_b   = (const float*)d_in[19];
    const float* gn1_w = (const float*)d_in[20];
    const float* gn1_b = (const float*)d_in[21];
    const float* gn1_ms= (const float*)d_in[22];
    const float* gn2_w = (const float*)d_in[23];
    const float* gn2_b = (const float*)d_in[24];
    const float* gn2_ms= (const float*)d_in[25];
    const float* ln1_g = (const float*)d_in[26];
    const float* ln1_b = (const float*)d_in[27];
    const float* ln2_g = (const float*)d_in[28];
    const float* ln2_b = (const float*)d_in[29];
    const float* ffn1_w= (const float*)d_in[30];
    const float* ffn1_b= (const float*)d_in[31];
    const float* ffn2_w= (const float*)d_in[32];
    const float* ffn2_b= (const float*)d_in[33];

    const size_t NB = (size_t)N_NODES * D * sizeof(float);   // 51.2 MB
    // relation group size chosen by available workspace:
    //   RGRP=9: X holds all 9 relations (fastest, needs ~673 MB)
    //   RGRP=3: 3 passes over edges with Q/K/V RMW      (~365 MB)
    //   RGRP=1: 9 passes                                 (~263 MB)
    int RGRP = (ws_size >= 4 * NB + 9 * NB + 6600000) ? 9
             : (ws_size >= 4 * NB + 3 * NB + 6600000) ? 3 : 1;

    char* w = (char*)d_ws;
    float* hn = (float*)(w + 0 * NB);     // gn1 out; later attn out; later FFN hidden [0,2NB)
    float* Qb = (float*)(w + 1 * NB);
    float* Kb = (float*)(w + 2 * NB);
    float* Vb = (float*)(w + 3 * NB);
    float* Xb = (float*)(w + 4 * NB);     // RGRP*NB bytes
    char*  sm = w + 4 * NB + (size_t)RGRP * NB;
    float* Wt = (float*)sm;               // 128 x 1152 = 589824 B
    int* ecnt   = (int*)(sm + 589824);
    int* estart = ecnt + N_NODES;
    int* ecur   = estart + N_NODES;
    int* bsum   = ecur + N_NODES;         // 128 ints
    int* ssrc   = bsum + 128;
    int* setp   = ssrc + N_EDGES;

    const int EB = (N_EDGES + 255) / 256;      // 2344
    const int GB = (N_NODES + 63) / 64;        // 1563
    const int SB = (N_NODES + 1023) / 1024;    // 98
    const int WB = (N_NODES * 64 + 255) / 256; // 25000 (wave-per-node kernels)

    // ---- sort edges by dst (counting sort)
    hipMemsetAsync(ecnt, 0, N_NODES * sizeof(int), stream);
    hipMemsetAsync(ecur, 0, N_NODES * sizeof(int), stream);
    hist_kernel<<<EB, 256, 0, stream>>>(dst, ecnt);
    scan1_kernel<<<SB, 1024, 0, stream>>>(ecnt, estart, bsum, N_NODES);
    scan2_kernel<<<1, 128, 0, stream>>>(bsum, SB);
    scan3_kernel<<<SB, 1024, 0, stream>>>(estart, bsum, N_NODES);
    scatter_kernel<<<EB, 256, 0, stream>>>(src, dst, ety, estart, ecur, ssrc, setp);

    // ---- graph norm 1
    graphnorm_kernel<<<NG, 512, 0, stream>>>(h, seg, gn1_w, gn1_b, gn1_ms, hn);

    // ---- Q/K/V relconvs
    float* Pb[3] = {Qb, Kb, Vb};
    const int ngrp = 9 / RGRP;
    for (int p = 0; p < 3; ++p) {
        build_wt_kernel<<<(REL * D * D + 255) / 256, 256, 0, stream>>>(coeffs[p], bases[p], Wt);
        gemm_kernel<128, true, false><<<dim3(GB, 1), 256, 0, stream>>>(
            hn, loops[p], 128, 0, pbias[p], Pb[p], 128, N_NODES);
        for (int g = 0; g < ngrp; ++g) {
            gemm_kernel<128, false, false><<<dim3(GB, RGRP), 256, 0, stream>>>(
                hn, Wt, REL * D, g * RGRP * 128, nullptr, Xb, RGRP * 128, N_NODES);
            segsum_kernel<<<WB, 256, 0, stream>>>(
                Xb, RGRP * 128, ssrc, setp, estart, ecnt, Pb[p],
                g * RGRP, RGRP, (g == ngrp - 1) ? 1 : 0);
        }
    }

    // ---- attention (into hn; hn no longer needed)
    attn_kernel<<<WB, 256, 0, stream>>>(Qb, Kb, Vb, ssrc, estart, ecnt, hn);

    // ---- output projection + ln1
    gemm_kernel<128, true, false><<<dim3(GB, 1), 256, 0, stream>>>(
        hn, o_w, 128, 0, o_b, Qb, 128, N_NODES);
    ln_kernel<<<WB, 256, 0, stream>>>(Qb, ln1_g, ln1_b, Qb);

    // ---- graph norm 2
    graphnorm_kernel<<<NG, 512, 0, stream>>>(Qb, seg, gn2_w, gn2_b, gn2_ms, Kb);

    // ---- FFN (hidden into [0, 2NB) region; hn/Qb contents dead by now)
    gemm_kernel<128, true, true><<<dim3(GB, 2), 256, 0, stream>>>(
        Kb, ffn1_w, 256, 0, ffn1_b, hn, 256, N_NODES);
    gemm_kernel<256, true, false><<<dim3(GB, 1), 256, 0, stream>>>(
        hn, ffn2_w, 128, 0, ffn2_b, Vb, 128, N_NODES);

    // ---- final layernorm -> d_out
    ln_kernel<<<WB, 256, 0, stream>>>(Vb, ln2_g, ln2_b, (float*)d_out);
}

// Round 2
// 1094.133 us; speedup vs baseline: 3.7137x; 3.7137x over previous
//
#include <hip/hip_runtime.h>
#include <math.h>

#define N_NODES 100000
#define N_EDGES 600000
#define D 128
#define REL 9
#define NG 64

typedef float f32x4 __attribute__((ext_vector_type(4)));
typedef short s16x8 __attribute__((ext_vector_type(8)));

__device__ __forceinline__ ushort f2bf(float x) {
    union { float f; unsigned u; } c; c.f = x;
    unsigned r = c.u + 0x7FFFu + ((c.u >> 16) & 1u);
    return (ushort)(r >> 16);
}
__device__ __forceinline__ float bf2f(ushort h) {
    union { unsigned u; float f; } c; c.u = ((unsigned)h) << 16; return c.f;
}

__device__ __forceinline__ int lbound(const int* __restrict__ a, int n, int key) {
    int lo = 0, hi = n;
    while (lo < hi) { int mid = (lo + hi) >> 1; if (a[mid] < key) lo = mid + 1; else hi = mid; }
    return lo;
}

// ------------------------------------------------------------ edge sorting
__global__ void hist_kernel(const int* __restrict__ dst, int* __restrict__ cnt) {
    int e = blockIdx.x * 256 + threadIdx.x;
    if (e < N_EDGES) atomicAdd(&cnt[dst[e]], 1);
}

__global__ void scan1_kernel(const int* __restrict__ cnt, int* __restrict__ excl,
                             int* __restrict__ bsum, int n) {
    __shared__ int s[1024];
    int tid = threadIdx.x;
    int i = blockIdx.x * 1024 + tid;
    int v = (i < n) ? cnt[i] : 0;
    s[tid] = v;
    __syncthreads();
    for (int off = 1; off < 1024; off <<= 1) {
        int t = (tid >= off) ? s[tid - off] : 0;
        __syncthreads();
        s[tid] += t;
        __syncthreads();
    }
    if (i < n) excl[i] = s[tid] - v;
    if (tid == 1023) bsum[blockIdx.x] = s[1023];
}

__global__ void scan2_kernel(int* __restrict__ bsum, int nb) {
    __shared__ int s[128];
    int tid = threadIdx.x;
    int v = (tid < nb) ? bsum[tid] : 0;
    s[tid] = v;
    __syncthreads();
    for (int off = 1; off < 128; off <<= 1) {
        int t = (tid >= off) ? s[tid - off] : 0;
        __syncthreads();
        s[tid] += t;
        __syncthreads();
    }
    if (tid < nb) bsum[tid] = s[tid] - v;
}

__global__ void scan3_kernel(int* __restrict__ excl, const int* __restrict__ bsum, int n) {
    int i = blockIdx.x * 1024 + threadIdx.x;
    if (i < n) excl[i] += bsum[blockIdx.x];
}

__global__ void scatter_kernel(const int* __restrict__ src, const int* __restrict__ dst,
                               const int* __restrict__ ety, const int* __restrict__ estart,
                               int* __restrict__ cur, int* __restrict__ ssrc,
                               int* __restrict__ setp) {
    int e = blockIdx.x * 256 + threadIdx.x;
    if (e < N_EDGES) {
        int d = dst[e];
        int pos = estart[d] + atomicAdd(&cur[d], 1);
        ssrc[pos] = src[e];
        setp[pos] = ety[e];
    }
}

// ------------------------------------------------------------- graph norm (moment form)
__global__ __launch_bounds__(256)
void gn_stats(const float* __restrict__ x, const int* __restrict__ seg,
              float* __restrict__ gsum, float* __restrict__ gsumsq) {
    int ch = threadIdx.x & 127;
    int rr = threadIdx.x >> 7;
    int n0 = blockIdx.x * 128;
    int nend = min(n0 + 128, N_NODES);
    float sx = 0.f, sxx = 0.f;
    int cg = -1;
    for (int n = n0 + rr; n < nend; n += 2) {
        int g = seg[n];
        if (g != cg) {
            if (cg >= 0) { atomicAdd(&gsum[cg * D + ch], sx); atomicAdd(&gsumsq[cg * D + ch], sxx); }
            cg = g; sx = 0.f; sxx = 0.f;
        }
        float v = x[(size_t)n * D + ch];
        sx += v; sxx += v * v;
    }
    if (cg >= 0) { atomicAdd(&gsum[cg * D + ch], sx); atomicAdd(&gsumsq[cg * D + ch], sxx); }
}

__global__ void gn_final(const float* __restrict__ gsum, const float* __restrict__ gsumsq,
                         const int* __restrict__ seg, const float* __restrict__ w,
                         const float* __restrict__ b, const float* __restrict__ ms,
                         float* __restrict__ sc, float* __restrict__ off) {
    int g = blockIdx.x, ch = threadIdx.x;
    int lo = lbound(seg, N_NODES, g), hi = lbound(seg, N_NODES, g + 1);
    float cnt = (float)max(hi - lo, 1);
    float mean = gsum[g * D + ch] / cnt;
    float mm = mean * ms[ch];
    float var = gsumsq[g * D + ch] / cnt - 2.f * mm * mean + mm * mm;
    float rstd = rsqrtf(var + 1e-6f);
    float s = w[ch] * rstd;
    sc[g * D + ch] = s;
    off[g * D + ch] = b[ch] - s * mm;
}

__global__ __launch_bounds__(256)
void gn_apply(const float* __restrict__ x, const int* __restrict__ seg,
              const float* __restrict__ sc, const float* __restrict__ off,
              ushort* __restrict__ outbf) {
    int t = blockIdx.x * 256 + threadIdx.x;
    int n = t >> 6;
    if (n >= N_NODES) return;
    int ch = (t & 63) * 2;
    int g = seg[n];
    float2 xv = *(const float2*)&x[(size_t)n * D + ch];
    float2 s2 = *(const float2*)&sc[g * D + ch];
    float2 o2 = *(const float2*)&off[g * D + ch];
    ushort2 o;
    o.x = f2bf(s2.x * xv.x + o2.x);
    o.y = f2bf(s2.y * xv.y + o2.y);
    *(ushort2*)&outbf[(size_t)n * D + ch] = o;
}

// --------------------------------------------- combined QKV weight build (bf16, transposed)
// Bt[n=p*128+o][k] : k<128 -> loop_w[k][o] ; k=128+r*128+i -> sum_b coeff[r,b]*basis[b,i,o]
__global__ void build_bt_qkv(const float* __restrict__ coeff, const float* __restrict__ basis,
                             const float* __restrict__ loop_w, const float* __restrict__ bias_in,
                             ushort* __restrict__ Bt, float* __restrict__ bias_out) {
    int t = blockIdx.x * 256 + threadIdx.x;
    if (t < 128) bias_out[t] = bias_in[t];
    if (t >= 128 * 1280) return;
    int o = t / 1280;
    int k = t - o * 1280;
    float v;
    if (k < 128) {
        v = loop_w[k * 128 + o];
    } else {
        int kk = k - 128;
        int r = kk >> 7, i = kk & 127;
        v = 0.f;
#pragma unroll
        for (int b = 0; b < REL; ++b)
            v += coeff[r * REL + b] * basis[((size_t)b * 128 + i) * 128 + o];
    }
    Bt[(size_t)o * 1280 + k] = f2bf(v);
}

// W[I][O] fp32 -> Bt[O][I] bf16
__global__ void transpose_cast(const float* __restrict__ W, int I, int O, ushort* __restrict__ Bt) {
    int t = blockIdx.x * 256 + threadIdx.x;
    if (t >= I * O) return;
    int n = t / I, k = t - n * I;
    Bt[(size_t)n * I + k] = f2bf(W[(size_t)k * O + n]);
}

// ----------------------------------------- per-relation gathered sums -> A rows (bf16)
// A[n-c0] = [ hn[n] | S_0[n] | ... | S_8[n] ]   (1280 bf16)
__global__ __launch_bounds__(256)
void s_pass(const ushort* __restrict__ hnbf, const int* __restrict__ ssrc,
            const int* __restrict__ setp, const int* __restrict__ estart,
            const int* __restrict__ ecnt, ushort* __restrict__ Ab, int c0, int c1) {
    int n = c0 + ((blockIdx.x * 256 + threadIdx.x) >> 6);
    if (n >= c1) return;
    int lane = threadIdx.x & 63;
    int e0 = estart[n], e1 = e0 + ecnt[n];
    float ax0=0,ay0=0,ax1=0,ay1=0,ax2=0,ay2=0,ax3=0,ay3=0,ax4=0,ay4=0;
    float ax5=0,ay5=0,ax6=0,ay6=0,ax7=0,ay7=0,ax8=0,ay8=0;
    for (int e = e0; e < e1; ++e) {
        int s = ssrc[e];
        int r = __builtin_amdgcn_readfirstlane(setp[e]);   // edge-uniform across the wave
        ushort2 hv = *(const ushort2*)&hnbf[(size_t)s * D + 2 * lane];
        float vx = bf2f(hv.x), vy = bf2f(hv.y);
        switch (r) {
            case 0: ax0 += vx; ay0 += vy; break;
            case 1: ax1 += vx; ay1 += vy; break;
            case 2: ax2 += vx; ay2 += vy; break;
            case 3: ax3 += vx; ay3 += vy; break;
            case 4: ax4 += vx; ay4 += vy; break;
            case 5: ax5 += vx; ay5 += vy; break;
            case 6: ax6 += vx; ay6 += vy; break;
            case 7: ax7 += vx; ay7 += vy; break;
            default: ax8 += vx; ay8 += vy; break;
        }
    }
    ushort* arow = Ab + (size_t)(n - c0) * 1280;
    *(ushort2*)&arow[2 * lane] = *(const ushort2*)&hnbf[(size_t)n * D + 2 * lane];
    ushort2 t;
#define ST(r) t.x = f2bf(ax##r); t.y = f2bf(ay##r); *(ushort2*)&arow[128 + r * 128 + 2 * lane] = t;
    ST(0) ST(1) ST(2) ST(3) ST(4) ST(5) ST(6) ST(7) ST(8)
#undef ST
}

// ----------------------------------------------------------------- bf16 MFMA GEMM
// C[m][n] = sum_k A[m][k] * Bt[n][k] (+bias[n]) ; block 128x128, 4 waves 2x2, each 64x64.
template<bool RELU, bool BF16OUT>
__global__ __launch_bounds__(256)
void mfma_gemm(const ushort* __restrict__ A, int lda, int M,
               const ushort* __restrict__ Bt, int K,
               const float* __restrict__ bias, void* __restrict__ Cout, int ldc) {
    __shared__ ushort As[128 * 40];   // rows padded to 40 shorts (2-way-free banks)
    __shared__ ushort Bs[128 * 40];
    const int tid = threadIdx.x;
    const int lane = tid & 63;
    const int wave = tid >> 6;
    const int wm = wave & 1, wn = wave >> 1;
    const int quad = lane >> 4, l16 = lane & 15;
    const int row0 = blockIdx.x * 128, col0 = blockIdx.y * 128;

    const int srow = tid >> 1;
    const int sseg = (tid & 1) * 16;             // shorts
    const ushort* Ap = A + (size_t)(row0 + srow) * lda + sseg;
    const ushort* Bp = Bt + (size_t)(col0 + srow) * K + sseg;
    const bool aval = (row0 + srow) < M;

    f32x4 acc[4][4];
#pragma unroll
    for (int i = 0; i < 4; ++i)
#pragma unroll
        for (int j = 0; j < 4; ++j) acc[i][j] = (f32x4){0.f, 0.f, 0.f, 0.f};

    for (int kc = 0; kc < K; kc += 32) {
        uint4 av0 = make_uint4(0, 0, 0, 0), av1 = av0;
        if (aval) {
            av0 = *(const uint4*)(Ap + kc);
            av1 = *(const uint4*)(Ap + kc + 8);
        }
        uint4 bv0 = *(const uint4*)(Bp + kc);
        uint4 bv1 = *(const uint4*)(Bp + kc + 8);
        if (kc) __syncthreads();
        *(uint4*)&As[srow * 40 + sseg] = av0;
        *(uint4*)&As[srow * 40 + sseg + 8] = av1;
        *(uint4*)&Bs[srow * 40 + sseg] = bv0;
        *(uint4*)&Bs[srow * 40 + sseg + 8] = bv1;
        __syncthreads();
        s16x8 af[4], bf[4];
#pragma unroll
        for (int i = 0; i < 4; ++i)
            af[i] = *(const s16x8*)&As[(wm * 64 + i * 16 + l16) * 40 + quad * 8];
#pragma unroll
        for (int j = 0; j < 4; ++j)
            bf[j] = *(const s16x8*)&Bs[(wn * 64 + j * 16 + l16) * 40 + quad * 8];
#pragma unroll
        for (int i = 0; i < 4; ++i)
#pragma unroll
            for (int j = 0; j < 4; ++j)
                acc[i][j] = __builtin_amdgcn_mfma_f32_16x16x32_bf16(af[i], bf[j], acc[i][j], 0, 0, 0);
    }

#pragma unroll
    for (int i = 0; i < 4; ++i) {
        int gr0 = row0 + wm * 64 + i * 16 + quad * 4;
#pragma unroll
        for (int r = 0; r < 4; ++r) {
            int grow = gr0 + r;
            if (grow >= M) continue;
#pragma unroll
            for (int j = 0; j < 4; ++j) {
                int gcol = col0 + wn * 64 + j * 16 + l16;
                float v = acc[i][j][r] + bias[gcol];
                if (RELU) v = fmaxf(v, 0.f);
                if (BF16OUT) ((ushort*)Cout)[(size_t)grow * ldc + gcol] = f2bf(v);
                else         ((float*)Cout)[(size_t)grow * ldc + gcol] = v;
            }
        }
    }
}

// --------------------------------------------------------------- attention
__global__ __launch_bounds__(256)
void attn_kernel(const float* __restrict__ C, const int* __restrict__ ssrc,
                 const int* __restrict__ estart, const int* __restrict__ ecnt,
                 ushort* __restrict__ attnbf) {
    int n = (blockIdx.x * 256 + threadIdx.x) >> 6;
    if (n >= N_NODES) return;
    int lane = threadIdx.x & 63;
    const float2 q = *(const float2*)&C[(size_t)n * 384 + 2 * lane];
    int e0 = estart[n], e1 = e0 + ecnt[n];
    float wvx = 0.f, wvy = 0.f, z = 0.f;
    for (int e = e0; e < e1; ++e) {
        int s = ssrc[e];
        const float2 kv = *(const float2*)&C[(size_t)s * 384 + 128 + 2 * lane];
        float d = kv.x * q.x + kv.y * q.y;
        d += __shfl_xor(d, 1);
        d += __shfl_xor(d, 2);
        d += __shfl_xor(d, 4);
        float sc = fminf(fmaxf(d * 0.25f, -10.f), 10.f);
        sc = expf(sc);
        const float2 vv = *(const float2*)&C[(size_t)s * 384 + 256 + 2 * lane];
        wvx += sc * vv.x; wvy += sc * vv.y; z += sc;
    }
    float inv = 1.f / (z + 1e-6f);
    ushort2 o;
    o.x = f2bf(wvx * inv);
    o.y = f2bf(wvy * inv);
    *(ushort2*)&attnbf[(size_t)n * D + 2 * lane] = o;
}

// --------------------------------------------------------------- layernorm (fp32)
__global__ __launch_bounds__(256)
void ln_kernel(const float* __restrict__ x, const float* __restrict__ g,
               const float* __restrict__ b, float* __restrict__ out) {
    int n = (blockIdx.x * 256 + threadIdx.x) >> 6;
    if (n >= N_NODES) return;
    int lane = threadIdx.x & 63;
    float2 v = ((const float2*)&x[(size_t)n * D])[lane];
    float s = v.x + v.y;
#pragma unroll
    for (int off = 1; off < 64; off <<= 1) s += __shfl_xor(s, off);
    float mu = s * (1.f / 128.f);
    float dx = v.x - mu, dy = v.y - mu;
    float vs = dx * dx + dy * dy;
#pragma unroll
    for (int off = 1; off < 64; off <<= 1) vs += __shfl_xor(vs, off);
    float rstd = rsqrtf(vs * (1.f / 128.f) + 1e-5f);
    float2 gg = ((const float2*)g)[lane];
    float2 bb = ((const float2*)b)[lane];
    ((float2*)&out[(size_t)n * D])[lane] =
        make_float2(gg.x * dx * rstd + bb.x, gg.y * dy * rstd + bb.y);
}

// ------------------------------------------------------------------ launch
extern "C" void kernel_launch(void* const* d_in, const int* in_sizes, int n_in,
                              void* d_out, int out_size, void* d_ws, size_t ws_size,
                              hipStream_t stream) {
    (void)in_sizes; (void)n_in; (void)out_size;
    const float* h     = (const float*)d_in[0];
    const int*   src   = (const int*)d_in[1];
    const int*   dst   = (const int*)d_in[2];
    const int*   ety   = (const int*)d_in[3];
    const int*   seg   = (const int*)d_in[4];
    const float* coeffs[3] = {(const float*)d_in[6],  (const float*)d_in[10], (const float*)d_in[14]};
    const float* bases [3] = {(const float*)d_in[7],  (const float*)d_in[11], (const float*)d_in[15]};
    const float* loops [3] = {(const float*)d_in[8],  (const float*)d_in[12], (const float*)d_in[16]};
    const float* pbias [3] = {(const float*)d_in[9],  (const float*)d_in[13], (const float*)d_in[17]};
    const float* o_w   = (const float*)d_in[18];
    const float* o_b   = (const float*)d_in[19];
    const float* gn1_w = (const float*)d_in[20];
    const float* gn1_b = (const float*)d_in[21];
    const float* gn1_ms= (const float*)d_in[22];
    const float* gn2_w = (const float*)d_in[23];
    const float* gn2_b = (const float*)d_in[24];
    const float* gn2_ms= (const float*)d_in[25];
    const float* ln1_g = (const float*)d_in[26];
    const float* ln1_b = (const float*)d_in[27];
    const float* ln2_g = (const float*)d_in[28];
    const float* ln2_b = (const float*)d_in[29];
    const float* ffn1_w= (const float*)d_in[30];
    const float* ffn1_b= (const float*)d_in[31];
    const float* ffn2_w= (const float*)d_in[32];
    const float* ffn2_b= (const float*)d_in[33];

    char* p = (char*)d_ws;
    auto take = [&](size_t bytes) { char* r = p; p += (bytes + 255) & ~(size_t)255; return r; };
    int*    ecnt   = (int*)take((size_t)N_NODES * 4);
    int*    estart = (int*)take((size_t)N_NODES * 4);
    int*    ecur   = (int*)take((size_t)N_NODES * 4);
    int*    bsum   = (int*)take(512);
    int*    ssrc   = (int*)take((size_t)N_EDGES * 4);
    int*    setp   = (int*)take((size_t)N_EDGES * 4);
    float*  gsum   = (float*)take((size_t)NG * D * 4 * 2);
    float*  gsumsq = gsum + NG * D;
    float*  gsc    = (float*)take((size_t)NG * D * 4);
    float*  goff   = (float*)take((size_t)NG * D * 4);
    ushort* Btqkv  = (ushort*)take((size_t)384 * 1280 * 2);
    float*  biasq  = (float*)take(384 * 4);
    ushort* Bto    = (ushort*)take((size_t)128 * 128 * 2);
    ushort* Btf1   = (ushort*)take((size_t)256 * 128 * 2);
    ushort* Btf2   = (ushort*)take((size_t)128 * 256 * 2);
    ushort* hnbf   = (ushort*)take((size_t)N_NODES * D * 2);
    ushort* attnbf = (ushort*)take((size_t)N_NODES * D * 2);
    float*  Cqkv   = (float*)take((size_t)N_NODES * 384 * 4);
    size_t used = (size_t)(p - (char*)d_ws);
    size_t avail = (ws_size > used) ? ws_size - used : 0;
    int NC = 1;
    if (avail < (size_t)N_NODES * 1280 * 2) NC = 4;
    if (NC == 4 && avail < ((size_t)(N_NODES / 4 + 1) * 1280 * 2)) NC = 8;
    ushort* Ab = (ushort*)p;
    const int chunk = (N_NODES + NC - 1) / NC;

    // buffer reuse after their producers/consumers retire:
    float*  hO     = Cqkv;                                   // after attention, Cqkv dead
    ushort* gn2bf  = (ushort*)((char*)Cqkv + 51200000);
    ushort* ffn1bf = (ushort*)((char*)Cqkv + 76800000);
    float*  ffn2o  = (float*)hnbf;                           // hnbf+attnbf dead by then (51.2MB)

    const int EB = (N_EDGES + 255) / 256;
    const int SB = (N_NODES + 1023) / 1024;
    const int WB = (N_NODES * 64 + 255) / 256;               // wave-per-node kernels
    const int GB = (N_NODES + 127) / 128;

    // ---- sort edges by dst
    hipMemsetAsync(ecnt, 0, N_NODES * sizeof(int), stream);
    hipMemsetAsync(ecur, 0, N_NODES * sizeof(int), stream);
    hist_kernel<<<EB, 256, 0, stream>>>(dst, ecnt);
    scan1_kernel<<<SB, 1024, 0, stream>>>(ecnt, estart, bsum, N_NODES);
    scan2_kernel<<<1, 128, 0, stream>>>(bsum, SB);
    scan3_kernel<<<SB, 1024, 0, stream>>>(estart, bsum, N_NODES);
    scatter_kernel<<<EB, 256, 0, stream>>>(src, dst, ety, estart, ecur, ssrc, setp);

    // ---- weights (independent of node data)
    for (int pj = 0; pj < 3; ++pj)
        build_bt_qkv<<<640, 256, 0, stream>>>(coeffs[pj], bases[pj], loops[pj], pbias[pj],
                                              Btqkv + (size_t)pj * 128 * 1280, biasq + pj * 128);
    transpose_cast<<<64, 256, 0, stream>>>(o_w, 128, 128, Bto);
    transpose_cast<<<128, 256, 0, stream>>>(ffn1_w, 128, 256, Btf1);
    transpose_cast<<<128, 256, 0, stream>>>(ffn2_w, 256, 128, Btf2);

    // ---- graph norm 1 -> hnbf (bf16)
    hipMemsetAsync(gsum, 0, (size_t)NG * D * 8, stream);
    gn_stats<<<GB, 256, 0, stream>>>(h, seg, gsum, gsumsq);
    gn_final<<<NG, 128, 0, stream>>>(gsum, gsumsq, seg, gn1_w, gn1_b, gn1_ms, gsc, goff);
    gn_apply<<<WB, 256, 0, stream>>>(h, seg, gsc, goff, hnbf);

    // ---- QKV: S-pass + one big MFMA GEMM per chunk
    for (int c = 0; c < NC; ++c) {
        int c0 = c * chunk;
        int c1 = min(N_NODES, c0 + chunk);
        int rows = c1 - c0;
        if (rows <= 0) break;
        s_pass<<<(rows + 3) / 4, 256, 0, stream>>>(hnbf, ssrc, setp, estart, ecnt, Ab, c0, c1);
        mfma_gemm<true, false><<<dim3((rows + 127) / 128, 3), 256, 0, stream>>>(
            Ab, 1280, rows, Btqkv, 1280, biasq, Cqkv + (size_t)c0 * 384, 384);
    }

    // ---- attention
    attn_kernel<<<WB, 256, 0, stream>>>(Cqkv, ssrc, estart, ecnt, attnbf);

    // ---- output projection + ln1 (in-place)
    mfma_gemm<false, false><<<dim3((N_NODES + 127) / 128, 1), 256, 0, stream>>>(
        attnbf, 128, N_NODES, Bto, 128, o_b, hO, 128);
    ln_kernel<<<WB, 256, 0, stream>>>(hO, ln1_g, ln1_b, hO);

    // ---- graph norm 2 -> gn2bf
    hipMemsetAsync(gsum, 0, (size_t)NG * D * 8, stream);
    gn_stats<<<GB, 256, 0, stream>>>(hO, seg, gsum, gsumsq);
    gn_final<<<NG, 128, 0, stream>>>(gsum, gsumsq, seg, gn2_w, gn2_b, gn2_ms, gsc, goff);
    gn_apply<<<WB, 256, 0, stream>>>(hO, seg, gsc, goff, gn2bf);

    // ---- FFN
    mfma_gemm<true, true><<<dim3((N_NODES + 127) / 128, 2), 256, 0, stream>>>(
        gn2bf, 128, N_NODES, Btf1, 128, ffn1_b, ffn1bf, 256);
    mfma_gemm<false, false><<<dim3((N_NODES + 127) / 128, 1), 256, 0, stream>>>(
        ffn1bf, 256, N_NODES, Btf2, 256, ffn2_b, ffn2o, 128);

    // ---- final layernorm -> d_out
    ln_kernel<<<WB, 256, 0, stream>>>(ffn2o, ln2_g, ln2_b, (float*)d_out);
}

// Round 3
// 925.260 us; speedup vs baseline: 4.3916x; 1.1825x over previous
//
#include <hip/hip_runtime.h>
#include <math.h>

#define N_NODES 100000
#define N_EDGES 600000
#define D 128
#define REL 9
#define NG 64

typedef float f32x4 __attribute__((ext_vector_type(4)));
typedef _Float16 f16x8 __attribute__((ext_vector_type(8)));

__device__ __forceinline__ ushort f2h(float x) {
    union { _Float16 h; ushort u; } c; c.h = (_Float16)x; return c.u;
}
__device__ __forceinline__ float h2f(ushort u) {
    union { ushort u; _Float16 h; } c; c.u = u; return (float)c.h;
}

__device__ __forceinline__ int lbound(const int* __restrict__ a, int n, int key) {
    int lo = 0, hi = n;
    while (lo < hi) { int mid = (lo + hi) >> 1; if (a[mid] < key) lo = mid + 1; else hi = mid; }
    return lo;
}

// ------------------------------------------------------------ edge sorting
__global__ void hist_kernel(const int* __restrict__ dst, int* __restrict__ cnt) {
    int e = blockIdx.x * 256 + threadIdx.x;
    if (e < N_EDGES) atomicAdd(&cnt[dst[e]], 1);
}

__global__ void scan1_kernel(const int* __restrict__ cnt, int* __restrict__ excl,
                             int* __restrict__ bsum, int n) {
    __shared__ int s[1024];
    int tid = threadIdx.x;
    int i = blockIdx.x * 1024 + tid;
    int v = (i < n) ? cnt[i] : 0;
    s[tid] = v;
    __syncthreads();
    for (int off = 1; off < 1024; off <<= 1) {
        int t = (tid >= off) ? s[tid - off] : 0;
        __syncthreads();
        s[tid] += t;
        __syncthreads();
    }
    if (i < n) excl[i] = s[tid] - v;
    if (tid == 1023) bsum[blockIdx.x] = s[1023];
}

__global__ void scan2_kernel(int* __restrict__ bsum, int nb) {
    __shared__ int s[128];
    int tid = threadIdx.x;
    int v = (tid < nb) ? bsum[tid] : 0;
    s[tid] = v;
    __syncthreads();
    for (int off = 1; off < 128; off <<= 1) {
        int t = (tid >= off) ? s[tid - off] : 0;
        __syncthreads();
        s[tid] += t;
        __syncthreads();
    }
    if (tid < nb) bsum[tid] = s[tid] - v;
}

__global__ void scan3_kernel(int* __restrict__ excl, const int* __restrict__ bsum, int n) {
    int i = blockIdx.x * 1024 + threadIdx.x;
    if (i < n) excl[i] += bsum[blockIdx.x];
}

__global__ void scatter_kernel(const int* __restrict__ src, const int* __restrict__ dst,
                               const int* __restrict__ ety, const int* __restrict__ estart,
                               int* __restrict__ cur, int* __restrict__ ssrc,
                               int* __restrict__ setp) {
    int e = blockIdx.x * 256 + threadIdx.x;
    if (e < N_EDGES) {
        int d = dst[e];
        int pos = estart[d] + atomicAdd(&cur[d], 1);
        ssrc[pos] = src[e];
        setp[pos] = ety[e];
    }
}

// ------------------------------------------------------------- graph norm (moment form)
__global__ __launch_bounds__(256)
void gn_stats(const float* __restrict__ x, const int* __restrict__ seg,
              float* __restrict__ gsum, float* __restrict__ gsumsq) {
    int ch = threadIdx.x & 127;
    int rr = threadIdx.x >> 7;
    int n0 = blockIdx.x * 128;
    int nend = min(n0 + 128, N_NODES);
    float sx = 0.f, sxx = 0.f;
    int cg = -1;
    for (int n = n0 + rr; n < nend; n += 2) {
        int g = seg[n];
        if (g != cg) {
            if (cg >= 0) { atomicAdd(&gsum[cg * D + ch], sx); atomicAdd(&gsumsq[cg * D + ch], sxx); }
            cg = g; sx = 0.f; sxx = 0.f;
        }
        float v = x[(size_t)n * D + ch];
        sx += v; sxx += v * v;
    }
    if (cg >= 0) { atomicAdd(&gsum[cg * D + ch], sx); atomicAdd(&gsumsq[cg * D + ch], sxx); }
}

__global__ void gn_final(const float* __restrict__ gsum, const float* __restrict__ gsumsq,
                         const int* __restrict__ seg, const float* __restrict__ w,
                         const float* __restrict__ b, const float* __restrict__ ms,
                         float* __restrict__ sc, float* __restrict__ off) {
    int g = blockIdx.x, ch = threadIdx.x;
    int lo = lbound(seg, N_NODES, g), hi = lbound(seg, N_NODES, g + 1);
    float cnt = (float)max(hi - lo, 1);
    float mean = gsum[g * D + ch] / cnt;
    float mm = mean * ms[ch];
    float var = gsumsq[g * D + ch] / cnt - 2.f * mm * mean + mm * mm;
    float rstd = rsqrtf(var + 1e-6f);
    float s = w[ch] * rstd;
    sc[g * D + ch] = s;
    off[g * D + ch] = b[ch] - s * mm;
}

__global__ __launch_bounds__(256)
void gn_apply(const float* __restrict__ x, const int* __restrict__ seg,
              const float* __restrict__ sc, const float* __restrict__ off,
              ushort* __restrict__ outhf) {
    int t = blockIdx.x * 256 + threadIdx.x;
    int n = t >> 6;
    if (n >= N_NODES) return;
    int ch = (t & 63) * 2;
    int g = seg[n];
    float2 xv = *(const float2*)&x[(size_t)n * D + ch];
    float2 s2 = *(const float2*)&sc[g * D + ch];
    float2 o2 = *(const float2*)&off[g * D + ch];
    ushort2 o;
    o.x = f2h(s2.x * xv.x + o2.x);
    o.y = f2h(s2.y * xv.y + o2.y);
    *(ushort2*)&outhf[(size_t)n * D + ch] = o;
}

// --------------------------------------------- combined QKV weight build (fp16, transposed)
__global__ void build_bt_qkv(const float* __restrict__ coeff, const float* __restrict__ basis,
                             const float* __restrict__ loop_w, const float* __restrict__ bias_in,
                             ushort* __restrict__ Bt, float* __restrict__ bias_out) {
    int t = blockIdx.x * 256 + threadIdx.x;
    if (t < 128) bias_out[t] = bias_in[t];
    if (t >= 128 * 1280) return;
    int o = t / 1280;
    int k = t - o * 1280;
    float v;
    if (k < 128) {
        v = loop_w[k * 128 + o];
    } else {
        int kk = k - 128;
        int r = kk >> 7, i = kk & 127;
        v = 0.f;
#pragma unroll
        for (int b = 0; b < REL; ++b)
            v += coeff[r * REL + b] * basis[((size_t)b * 128 + i) * 128 + o];
    }
    Bt[(size_t)o * 1280 + k] = f2h(v);
}

__global__ void transpose_cast(const float* __restrict__ W, int I, int O, ushort* __restrict__ Bt) {
    int t = blockIdx.x * 256 + threadIdx.x;
    if (t >= I * O) return;
    int n = t / I, k = t - n * I;
    Bt[(size_t)n * I + k] = f2h(W[(size_t)k * O + n]);
}

// ----------------------------------------- per-relation gathered sums -> A rows (fp16)
__global__ __launch_bounds__(256)
void s_pass(const ushort* __restrict__ hnhf, const int* __restrict__ ssrc,
            const int* __restrict__ setp, const int* __restrict__ estart,
            const int* __restrict__ ecnt, ushort* __restrict__ Ab, int c0, int c1) {
    int n = c0 + ((blockIdx.x * 256 + threadIdx.x) >> 6);
    if (n >= c1) return;
    int lane = threadIdx.x & 63;
    int e0 = estart[n], e1 = e0 + ecnt[n];
    float ax0=0,ay0=0,ax1=0,ay1=0,ax2=0,ay2=0,ax3=0,ay3=0,ax4=0,ay4=0;
    float ax5=0,ay5=0,ax6=0,ay6=0,ax7=0,ay7=0,ax8=0,ay8=0;
    for (int e = e0; e < e1; ++e) {
        int s = ssrc[e];
        int r = __builtin_amdgcn_readfirstlane(setp[e]);   // edge-uniform across the wave
        ushort2 hv = *(const ushort2*)&hnhf[(size_t)s * D + 2 * lane];
        float vx = h2f(hv.x), vy = h2f(hv.y);
        switch (r) {
            case 0: ax0 += vx; ay0 += vy; break;
            case 1: ax1 += vx; ay1 += vy; break;
            case 2: ax2 += vx; ay2 += vy; break;
            case 3: ax3 += vx; ay3 += vy; break;
            case 4: ax4 += vx; ay4 += vy; break;
            case 5: ax5 += vx; ay5 += vy; break;
            case 6: ax6 += vx; ay6 += vy; break;
            case 7: ax7 += vx; ay7 += vy; break;
            default: ax8 += vx; ay8 += vy; break;
        }
    }
    ushort* arow = Ab + (size_t)(n - c0) * 1280;
    *(ushort2*)&arow[2 * lane] = *(const ushort2*)&hnhf[(size_t)n * D + 2 * lane];
    ushort2 t;
#define ST(r) t.x = f2h(ax##r); t.y = f2h(ay##r); *(ushort2*)&arow[128 + r * 128 + 2 * lane] = t;
    ST(0) ST(1) ST(2) ST(3) ST(4) ST(5) ST(6) ST(7) ST(8)
#undef ST
}

// ----------------------------------------------------------------- fp16 MFMA GEMM
// C[m][n] = sum_k A[m][k] * Bt[n][k] (+bias[n]) ; block 128x128, 4 waves 2x2, each 64x64.
template<bool RELU, bool F16OUT>
__global__ __launch_bounds__(256)
void mfma_gemm(const ushort* __restrict__ A, int lda, int M,
               const ushort* __restrict__ Bt, int K,
               const float* __restrict__ bias, void* __restrict__ Cout, int ldc) {
    __shared__ ushort As[128 * 40];
    __shared__ ushort Bs[128 * 40];
    const int tid = threadIdx.x;
    const int lane = tid & 63;
    const int wave = tid >> 6;
    const int wm = wave & 1, wn = wave >> 1;
    const int quad = lane >> 4, l16 = lane & 15;
    const int row0 = blockIdx.x * 128, col0 = blockIdx.y * 128;

    const int srow = tid >> 1;
    const int sseg = (tid & 1) * 16;
    const ushort* Ap = A + (size_t)(row0 + srow) * lda + sseg;
    const ushort* Bp = Bt + (size_t)(col0 + srow) * K + sseg;
    const bool aval = (row0 + srow) < M;

    f32x4 acc[4][4];
#pragma unroll
    for (int i = 0; i < 4; ++i)
#pragma unroll
        for (int j = 0; j < 4; ++j) acc[i][j] = (f32x4){0.f, 0.f, 0.f, 0.f};

    for (int kc = 0; kc < K; kc += 32) {
        uint4 av0 = make_uint4(0, 0, 0, 0), av1 = av0;
        if (aval) {
            av0 = *(const uint4*)(Ap + kc);
            av1 = *(const uint4*)(Ap + kc + 8);
        }
        uint4 bv0 = *(const uint4*)(Bp + kc);
        uint4 bv1 = *(const uint4*)(Bp + kc + 8);
        if (kc) __syncthreads();
        *(uint4*)&As[srow * 40 + sseg] = av0;
        *(uint4*)&As[srow * 40 + sseg + 8] = av1;
        *(uint4*)&Bs[srow * 40 + sseg] = bv0;
        *(uint4*)&Bs[srow * 40 + sseg + 8] = bv1;
        __syncthreads();
        f16x8 af[4], bf[4];
#pragma unroll
        for (int i = 0; i < 4; ++i)
            af[i] = *(const f16x8*)&As[(wm * 64 + i * 16 + l16) * 40 + quad * 8];
#pragma unroll
        for (int j = 0; j < 4; ++j)
            bf[j] = *(const f16x8*)&Bs[(wn * 64 + j * 16 + l16) * 40 + quad * 8];
#pragma unroll
        for (int i = 0; i < 4; ++i)
#pragma unroll
            for (int j = 0; j < 4; ++j)
                acc[i][j] = __builtin_amdgcn_mfma_f32_16x16x32_f16(af[i], bf[j], acc[i][j], 0, 0, 0);
    }

#pragma unroll
    for (int i = 0; i < 4; ++i) {
        int gr0 = row0 + wm * 64 + i * 16 + quad * 4;
#pragma unroll
        for (int r = 0; r < 4; ++r) {
            int grow = gr0 + r;
            if (grow >= M) continue;
#pragma unroll
            for (int j = 0; j < 4; ++j) {
                int gcol = col0 + wn * 64 + j * 16 + l16;
                float v = acc[i][j][r] + bias[gcol];
                if (RELU) v = fmaxf(v, 0.f);
                if (F16OUT) ((ushort*)Cout)[(size_t)grow * ldc + gcol] = f2h(v);
                else        ((float*)Cout)[(size_t)grow * ldc + gcol] = v;
            }
        }
    }
}

// --------------------------------------------------------------- attention (fp16 in/out)
__global__ __launch_bounds__(256)
void attn_kernel(const ushort* __restrict__ C, const int* __restrict__ ssrc,
                 const int* __restrict__ estart, const int* __restrict__ ecnt,
                 ushort* __restrict__ attnhf) {
    int n = (blockIdx.x * 256 + threadIdx.x) >> 6;
    if (n >= N_NODES) return;
    int lane = threadIdx.x & 63;
    ushort2 qh = *(const ushort2*)&C[(size_t)n * 384 + 2 * lane];
    float qx = h2f(qh.x), qy = h2f(qh.y);
    int e0 = estart[n], e1 = e0 + ecnt[n];
    float wvx = 0.f, wvy = 0.f, z = 0.f;
    for (int e = e0; e < e1; ++e) {
        int s = ssrc[e];
        ushort2 kh = *(const ushort2*)&C[(size_t)s * 384 + 128 + 2 * lane];
        float d = h2f(kh.x) * qx + h2f(kh.y) * qy;
        d += __shfl_xor(d, 1);
        d += __shfl_xor(d, 2);
        d += __shfl_xor(d, 4);
        float sc = fminf(fmaxf(d * 0.25f, -10.f), 10.f);
        sc = expf(sc);
        ushort2 vh = *(const ushort2*)&C[(size_t)s * 384 + 256 + 2 * lane];
        wvx += sc * h2f(vh.x); wvy += sc * h2f(vh.y); z += sc;
    }
    float inv = 1.f / (z + 1e-6f);
    ushort2 o;
    o.x = f2h(wvx * inv);
    o.y = f2h(wvy * inv);
    *(ushort2*)&attnhf[(size_t)n * D + 2 * lane] = o;
}

// --------------------------------------------------------------- layernorm (fp32)
__global__ __launch_bounds__(256)
void ln_kernel(const float* __restrict__ x, const float* __restrict__ g,
               const float* __restrict__ b, float* __restrict__ out) {
    int n = (blockIdx.x * 256 + threadIdx.x) >> 6;
    if (n >= N_NODES) return;
    int lane = threadIdx.x & 63;
    float2 v = ((const float2*)&x[(size_t)n * D])[lane];
    float s = v.x + v.y;
#pragma unroll
    for (int off = 1; off < 64; off <<= 1) s += __shfl_xor(s, off);
    float mu = s * (1.f / 128.f);
    float dx = v.x - mu, dy = v.y - mu;
    float vs = dx * dx + dy * dy;
#pragma unroll
    for (int off = 1; off < 64; off <<= 1) vs += __shfl_xor(vs, off);
    float rstd = rsqrtf(vs * (1.f / 128.f) + 1e-5f);
    float2 gg = ((const float2*)g)[lane];
    float2 bb = ((const float2*)b)[lane];
    ((float2*)&out[(size_t)n * D])[lane] =
        make_float2(gg.x * dx * rstd + bb.x, gg.y * dy * rstd + bb.y);
}

// ------------------------------------------------------------------ launch
extern "C" void kernel_launch(void* const* d_in, const int* in_sizes, int n_in,
                              void* d_out, int out_size, void* d_ws, size_t ws_size,
                              hipStream_t stream) {
    (void)in_sizes; (void)n_in; (void)out_size;
    const float* h     = (const float*)d_in[0];
    const int*   src   = (const int*)d_in[1];
    const int*   dst   = (const int*)d_in[2];
    const int*   ety   = (const int*)d_in[3];
    const int*   seg   = (const int*)d_in[4];
    const float* coeffs[3] = {(const float*)d_in[6],  (const float*)d_in[10], (const float*)d_in[14]};
    const float* bases [3] = {(const float*)d_in[7],  (const float*)d_in[11], (const float*)d_in[15]};
    const float* loops [3] = {(const float*)d_in[8],  (const float*)d_in[12], (const float*)d_in[16]};
    const float* pbias [3] = {(const float*)d_in[9],  (const float*)d_in[13], (const float*)d_in[17]};
    const float* o_w   = (const float*)d_in[18];
    const float* o_b   = (const float*)d_in[19];
    const float* gn1_w = (const float*)d_in[20];
    const float* gn1_b = (const float*)d_in[21];
    const float* gn1_ms= (const float*)d_in[22];
    const float* gn2_w = (const float*)d_in[23];
    const float* gn2_b = (const float*)d_in[24];
    const float* gn2_ms= (const float*)d_in[25];
    const float* ln1_g = (const float*)d_in[26];
    const float* ln1_b = (const float*)d_in[27];
    const float* ln2_g = (const float*)d_in[28];
    const float* ln2_b = (const float*)d_in[29];
    const float* ffn1_w= (const float*)d_in[30];
    const float* ffn1_b= (const float*)d_in[31];
    const float* ffn2_w= (const float*)d_in[32];
    const float* ffn2_b= (const float*)d_in[33];

    char* p = (char*)d_ws;
    auto take = [&](size_t bytes) { char* r = p; p += (bytes + 255) & ~(size_t)255; return r; };
    int*    ecnt   = (int*)take((size_t)N_NODES * 4);
    int*    estart = (int*)take((size_t)N_NODES * 4);
    int*    ecur   = (int*)take((size_t)N_NODES * 4);
    int*    bsum   = (int*)take(512);
    int*    ssrc   = (int*)take((size_t)N_EDGES * 4);
    int*    setp   = (int*)take((size_t)N_EDGES * 4);
    float*  gsum   = (float*)take((size_t)NG * D * 4 * 2);
    float*  gsumsq = gsum + NG * D;
    float*  gsc    = (float*)take((size_t)NG * D * 4);
    float*  goff   = (float*)take((size_t)NG * D * 4);
    ushort* Btqkv  = (ushort*)take((size_t)384 * 1280 * 2);
    float*  biasq  = (float*)take(384 * 4);
    ushort* Bto    = (ushort*)take((size_t)128 * 128 * 2);
    ushort* Btf1   = (ushort*)take((size_t)256 * 128 * 2);
    ushort* Btf2   = (ushort*)take((size_t)128 * 256 * 2);
    ushort* hnhf   = (ushort*)take((size_t)N_NODES * D * 2);     // 25.6 MB
    ushort* attnhf = (ushort*)take((size_t)N_NODES * D * 2);     // 25.6 MB (contiguous after hnhf)
    ushort* Cqkv   = (ushort*)take((size_t)N_NODES * 384 * 2);   // 76.8 MB
    float*  hO     = (float*)take((size_t)N_NODES * D * 4);      // 51.2 MB
    size_t used = (size_t)(p - (char*)d_ws);
    size_t avail = (ws_size > used) ? ws_size - used : 0;
    int NC = 1;
    if (avail < (size_t)N_NODES * 1280 * 2) NC = 4;
    if (NC == 4 && avail < ((size_t)(N_NODES / 4 + 1) * 1280 * 2)) NC = 8;
    ushort* Ab = (ushort*)p;
    const int chunk = (N_NODES + NC - 1) / NC;

    // dead-buffer aliases (see sequencing comments below):
    ushort* gn2hf  = Cqkv;                                // Cqkv dead after attention
    ushort* ffn1hf = (ushort*)((char*)Cqkv + 25600000);   // fits: 25.6+51.2 = 76.8 MB
    float*  ffn2o  = (float*)hnhf;                        // hnhf+attnhf (51.2 MB) dead by FFN2

    const int EB = (N_EDGES + 255) / 256;
    const int SB = (N_NODES + 1023) / 1024;
    const int WB = (N_NODES * 64 + 255) / 256;
    const int GB = (N_NODES + 127) / 128;

    // ---- sort edges by dst
    hipMemsetAsync(ecnt, 0, N_NODES * sizeof(int), stream);
    hipMemsetAsync(ecur, 0, N_NODES * sizeof(int), stream);
    hist_kernel<<<EB, 256, 0, stream>>>(dst, ecnt);
    scan1_kernel<<<SB, 1024, 0, stream>>>(ecnt, estart, bsum, N_NODES);
    scan2_kernel<<<1, 128, 0, stream>>>(bsum, SB);
    scan3_kernel<<<SB, 1024, 0, stream>>>(estart, bsum, N_NODES);
    scatter_kernel<<<EB, 256, 0, stream>>>(src, dst, ety, estart, ecur, ssrc, setp);

    // ---- weights
    for (int pj = 0; pj < 3; ++pj)
        build_bt_qkv<<<640, 256, 0, stream>>>(coeffs[pj], bases[pj], loops[pj], pbias[pj],
                                              Btqkv + (size_t)pj * 128 * 1280, biasq + pj * 128);
    transpose_cast<<<64, 256, 0, stream>>>(o_w, 128, 128, Bto);
    transpose_cast<<<128, 256, 0, stream>>>(ffn1_w, 128, 256, Btf1);
    transpose_cast<<<128, 256, 0, stream>>>(ffn2_w, 256, 128, Btf2);

    // ---- graph norm 1 -> hnhf (fp16)
    hipMemsetAsync(gsum, 0, (size_t)NG * D * 8, stream);
    gn_stats<<<GB, 256, 0, stream>>>(h, seg, gsum, gsumsq);
    gn_final<<<NG, 128, 0, stream>>>(gsum, gsumsq, seg, gn1_w, gn1_b, gn1_ms, gsc, goff);
    gn_apply<<<WB, 256, 0, stream>>>(h, seg, gsc, goff, hnhf);

    // ---- QKV: S-pass + one big MFMA GEMM per chunk -> Cqkv (fp16)
    for (int c = 0; c < NC; ++c) {
        int c0 = c * chunk;
        int c1 = min(N_NODES, c0 + chunk);
        int rows = c1 - c0;
        if (rows <= 0) break;
        s_pass<<<(rows + 3) / 4, 256, 0, stream>>>(hnhf, ssrc, setp, estart, ecnt, Ab, c0, c1);
        mfma_gemm<true, true><<<dim3((rows + 127) / 128, 3), 256, 0, stream>>>(
            Ab, 1280, rows, Btqkv, 1280, biasq, Cqkv + (size_t)c0 * 384, 384);
    }

    // ---- attention -> attnhf (fp16); Cqkv dead after this
    attn_kernel<<<WB, 256, 0, stream>>>(Cqkv, ssrc, estart, ecnt, attnhf);

    // ---- output projection (fp32 out) + ln1 in-place
    mfma_gemm<false, false><<<dim3((N_NODES + 127) / 128, 1), 256, 0, stream>>>(
        attnhf, 128, N_NODES, Bto, 128, o_b, hO, 128);
    ln_kernel<<<WB, 256, 0, stream>>>(hO, ln1_g, ln1_b, hO);

    // ---- graph norm 2 -> gn2hf (fp16, in dead Cqkv region)
    hipMemsetAsync(gsum, 0, (size_t)NG * D * 8, stream);
    gn_stats<<<GB, 256, 0, stream>>>(hO, seg, gsum, gsumsq);
    gn_final<<<NG, 128, 0, stream>>>(gsum, gsumsq, seg, gn2_w, gn2_b, gn2_ms, gsc, goff);
    gn_apply<<<WB, 256, 0, stream>>>(hO, seg, gsc, goff, gn2hf);

    // ---- FFN
    mfma_gemm<true, true><<<dim3((N_NODES + 127) / 128, 2), 256, 0, stream>>>(
        gn2hf, 128, N_NODES, Btf1, 128, ffn1_b, ffn1hf, 256);
    mfma_gemm<false, false><<<dim3((N_NODES + 127) / 128, 1), 256, 0, stream>>>(
        ffn1hf, 256, N_NODES, Btf2, 256, ffn2_b, ffn2o, 128);

    // ---- final layernorm -> d_out
    ln_kernel<<<WB, 256, 0, stream>>>(ffn2o, ln2_g, ln2_b, (float*)d_out);
}

// Round 4
// 851.909 us; speedup vs baseline: 4.7697x; 1.0861x over previous
//
#include <hip/hip_runtime.h>
#include <math.h>

#define N_NODES 100000
#define N_EDGES 600000
#define D 128
#define REL 9
#define NG 64

typedef float f32x4 __attribute__((ext_vector_type(4)));
typedef _Float16 f16x8 __attribute__((ext_vector_type(8)));

__device__ __forceinline__ ushort f2h(float x) {
    union { _Float16 h; ushort u; } c; c.h = (_Float16)x; return c.u;
}
__device__ __forceinline__ float h2f(ushort u) {
    union { ushort u; _Float16 h; } c; c.u = u; return (float)c.h;
}

// async global->LDS, 16 B per lane; dest = lds base (wave-uniform) + lane*16
__device__ __forceinline__ void ld16(const ushort* g, ushort* l) {
    __builtin_amdgcn_global_load_lds(
        (const __attribute__((address_space(1))) unsigned int*)g,
        (__attribute__((address_space(3))) unsigned int*)l, 16, 0, 0);
}

__device__ __forceinline__ int lbound(const int* __restrict__ a, int n, int key) {
    int lo = 0, hi = n;
    while (lo < hi) { int mid = (lo + hi) >> 1; if (a[mid] < key) lo = mid + 1; else hi = mid; }
    return lo;
}

// ------------------------------------------------------------ edge sorting
__global__ void hist_kernel(const int* __restrict__ dst, int* __restrict__ cnt) {
    int e = blockIdx.x * 256 + threadIdx.x;
    if (e < N_EDGES) atomicAdd(&cnt[dst[e]], 1);
}

__global__ void scan1_kernel(const int* __restrict__ cnt, int* __restrict__ excl,
                             int* __restrict__ bsum, int n) {
    __shared__ int s[1024];
    int tid = threadIdx.x;
    int i = blockIdx.x * 1024 + tid;
    int v = (i < n) ? cnt[i] : 0;
    s[tid] = v;
    __syncthreads();
    for (int off = 1; off < 1024; off <<= 1) {
        int t = (tid >= off) ? s[tid - off] : 0;
        __syncthreads();
        s[tid] += t;
        __syncthreads();
    }
    if (i < n) excl[i] = s[tid] - v;
    if (tid == 1023) bsum[blockIdx.x] = s[1023];
}

__global__ void scan2_kernel(int* __restrict__ bsum, int nb) {
    __shared__ int s[128];
    int tid = threadIdx.x;
    int v = (tid < nb) ? bsum[tid] : 0;
    s[tid] = v;
    __syncthreads();
    for (int off = 1; off < 128; off <<= 1) {
        int t = (tid >= off) ? s[tid - off] : 0;
        __syncthreads();
        s[tid] += t;
        __syncthreads();
    }
    if (tid < nb) bsum[tid] = s[tid] - v;
}

__global__ void scan3_kernel(int* __restrict__ excl, const int* __restrict__ bsum, int n) {
    int i = blockIdx.x * 1024 + threadIdx.x;
    if (i < n) excl[i] += bsum[blockIdx.x];
}

__global__ void scatter_kernel(const int* __restrict__ src, const int* __restrict__ dst,
                               const int* __restrict__ ety, const int* __restrict__ estart,
                               int* __restrict__ cur, int* __restrict__ ssrc,
                               int* __restrict__ setp) {
    int e = blockIdx.x * 256 + threadIdx.x;
    if (e < N_EDGES) {
        int d = dst[e];
        int pos = estart[d] + atomicAdd(&cur[d], 1);
        ssrc[pos] = src[e];
        setp[pos] = ety[e];
    }
}

// ------------------------------------------------------------- graph norm (moment form)
__global__ __launch_bounds__(256)
void gn_stats(const float* __restrict__ x, const int* __restrict__ seg,
              float* __restrict__ gsum, float* __restrict__ gsumsq) {
    int ch = threadIdx.x & 127;
    int rr = threadIdx.x >> 7;
    int n0 = blockIdx.x * 128;
    int nend = min(n0 + 128, N_NODES);
    float sx = 0.f, sxx = 0.f;
    int cg = -1;
    for (int n = n0 + rr; n < nend; n += 2) {
        int g = seg[n];
        if (g != cg) {
            if (cg >= 0) { atomicAdd(&gsum[cg * D + ch], sx); atomicAdd(&gsumsq[cg * D + ch], sxx); }
            cg = g; sx = 0.f; sxx = 0.f;
        }
        float v = x[(size_t)n * D + ch];
        sx += v; sxx += v * v;
    }
    if (cg >= 0) { atomicAdd(&gsum[cg * D + ch], sx); atomicAdd(&gsumsq[cg * D + ch], sxx); }
}

__global__ void gn_final(const float* __restrict__ gsum, const float* __restrict__ gsumsq,
                         const int* __restrict__ seg, const float* __restrict__ w,
                         const float* __restrict__ b, const float* __restrict__ ms,
                         float* __restrict__ sc, float* __restrict__ off) {
    int g = blockIdx.x, ch = threadIdx.x;
    int lo = lbound(seg, N_NODES, g), hi = lbound(seg, N_NODES, g + 1);
    float cnt = (float)max(hi - lo, 1);
    float mean = gsum[g * D + ch] / cnt;
    float mm = mean * ms[ch];
    float var = gsumsq[g * D + ch] / cnt - 2.f * mm * mean + mm * mm;
    float rstd = rsqrtf(var + 1e-6f);
    float s = w[ch] * rstd;
    sc[g * D + ch] = s;
    off[g * D + ch] = b[ch] - s * mm;
}

__global__ __launch_bounds__(256)
void gn_apply(const float* __restrict__ x, const int* __restrict__ seg,
              const float* __restrict__ sc, const float* __restrict__ off,
              ushort* __restrict__ outhf) {
    int t = blockIdx.x * 256 + threadIdx.x;
    int n = t >> 6;
    if (n >= N_NODES) return;
    int ch = (t & 63) * 2;
    int g = seg[n];
    float2 xv = *(const float2*)&x[(size_t)n * D + ch];
    float2 s2 = *(const float2*)&sc[g * D + ch];
    float2 o2 = *(const float2*)&off[g * D + ch];
    ushort2 o;
    o.x = f2h(s2.x * xv.x + o2.x);
    o.y = f2h(s2.y * xv.y + o2.y);
    *(ushort2*)&outhf[(size_t)n * D + ch] = o;
}

// --------------------------------------------- combined QKV weight build (fp16, transposed)
__global__ void build_bt_qkv(const float* __restrict__ coeff, const float* __restrict__ basis,
                             const float* __restrict__ loop_w, const float* __restrict__ bias_in,
                             ushort* __restrict__ Bt, float* __restrict__ bias_out) {
    int t = blockIdx.x * 256 + threadIdx.x;
    if (t < 128) bias_out[t] = bias_in[t];
    if (t >= 128 * 1280) return;
    int o = t / 1280;
    int k = t - o * 1280;
    float v;
    if (k < 128) {
        v = loop_w[k * 128 + o];
    } else {
        int kk = k - 128;
        int r = kk >> 7, i = kk & 127;
        v = 0.f;
#pragma unroll
        for (int b = 0; b < REL; ++b)
            v += coeff[r * REL + b] * basis[((size_t)b * 128 + i) * 128 + o];
    }
    Bt[(size_t)o * 1280 + k] = f2h(v);
}

__global__ void transpose_cast(const float* __restrict__ W, int I, int O, ushort* __restrict__ Bt) {
    int t = blockIdx.x * 256 + threadIdx.x;
    if (t >= I * O) return;
    int n = t / I, k = t - n * I;
    Bt[(size_t)n * I + k] = f2h(W[(size_t)k * O + n]);
}

// ----------------------------------------- per-relation gathered sums -> A rows (fp16)
__global__ __launch_bounds__(256)
void s_pass(const ushort* __restrict__ hnhf, const int* __restrict__ ssrc,
            const int* __restrict__ setp, const int* __restrict__ estart,
            const int* __restrict__ ecnt, ushort* __restrict__ Ab, int c0, int c1) {
    int n = c0 + ((blockIdx.x * 256 + threadIdx.x) >> 6);
    if (n >= c1) return;
    int lane = threadIdx.x & 63;
    int e0 = estart[n], e1 = e0 + ecnt[n];
    float ax0=0,ay0=0,ax1=0,ay1=0,ax2=0,ay2=0,ax3=0,ay3=0,ax4=0,ay4=0;
    float ax5=0,ay5=0,ax6=0,ay6=0,ax7=0,ay7=0,ax8=0,ay8=0;
    for (int e = e0; e < e1; ++e) {
        int s = ssrc[e];
        int r = __builtin_amdgcn_readfirstlane(setp[e]);   // edge-uniform across the wave
        ushort2 hv = *(const ushort2*)&hnhf[(size_t)s * D + 2 * lane];
        float vx = h2f(hv.x), vy = h2f(hv.y);
        switch (r) {
            case 0: ax0 += vx; ay0 += vy; break;
            case 1: ax1 += vx; ay1 += vy; break;
            case 2: ax2 += vx; ay2 += vy; break;
            case 3: ax3 += vx; ay3 += vy; break;
            case 4: ax4 += vx; ay4 += vy; break;
            case 5: ax5 += vx; ay5 += vy; break;
            case 6: ax6 += vx; ay6 += vy; break;
            case 7: ax7 += vx; ay7 += vy; break;
            default: ax8 += vx; ay8 += vy; break;
        }
    }
    ushort* arow = Ab + (size_t)(n - c0) * 1280;
    *(ushort2*)&arow[2 * lane] = *(const ushort2*)&hnhf[(size_t)n * D + 2 * lane];
    ushort2 t;
#define ST(r) t.x = f2h(ax##r); t.y = f2h(ay##r); *(ushort2*)&arow[128 + r * 128 + 2 * lane] = t;
    ST(0) ST(1) ST(2) ST(3) ST(4) ST(5) ST(6) ST(7) ST(8)
#undef ST
}

// ----------------------------------------------------------------- fp16 MFMA GEMM
// C[m][n] = sum_k A[m][k]*Bt[n][k] (+bias), m-tile 128, n-tile 128, k-step 64.
// Staging via global_load_lds (16 B/lane). LDS layout: row-major 128 rows x 128 B,
// 16-B chunk stored at slot (kg ^ (row&7)) -> lds-direct contiguity kept AND
// fragment ds_read_b128 lands 2-way on banks (free). grid: x=col blocks, y=row blocks.
template<bool RELU, bool F16OUT>
__global__ __launch_bounds__(256, 3)
void mfma_gemm(const ushort* __restrict__ A, int lda, int M,
               const ushort* __restrict__ Bt, int K,
               const float* __restrict__ bias, void* __restrict__ Cout, int ldc) {
    __shared__ ushort As[128 * 64];   // 16 KB
    __shared__ ushort Bs[128 * 64];   // 16 KB
    const int tid = threadIdx.x;
    const int lane = tid & 63;
    const int wave = tid >> 6;
    const int wm = wave & 1, wn = wave >> 1;
    const int quad = lane >> 4, l16 = lane & 15;
    const int col0 = blockIdx.x * 128, row0 = blockIdx.y * 128;

    // per-lane staging sources: instruction i of this wave covers local rows
    // (wave*4+i)*8 .. +8, 8 lanes per row, 16 B per lane (slot = lane&7).
    const ushort* sA[4];
    const ushort* sB[4];
#pragma unroll
    for (int i = 0; i < 4; ++i) {
        int rs = (wave * 4 + i) * 8 + (lane >> 3);   // local row 0..127
        int slot = lane & 7;
        int kg = slot ^ (rs & 7);                    // swizzled 16B chunk index
        int ra = row0 + rs; if (ra >= M) ra = M - 1; // clamp (rows only affect own C row)
        sA[i] = A + (size_t)ra * lda + kg * 8;
        sB[i] = Bt + (size_t)(col0 + rs) * K + kg * 8;
    }

    f32x4 acc[4][4];
#pragma unroll
    for (int i = 0; i < 4; ++i)
#pragma unroll
        for (int j = 0; j < 4; ++j) acc[i][j] = (f32x4){0.f, 0.f, 0.f, 0.f};

    for (int kc = 0; kc < K; kc += 64) {
#pragma unroll
        for (int i = 0; i < 4; ++i) {
            ld16(sA[i] + kc, &As[(wave * 4 + i) * 512]);
            ld16(sB[i] + kc, &Bs[(wave * 4 + i) * 512]);
        }
        __syncthreads();   // drains vmcnt -> LDS valid
#pragma unroll
        for (int h = 0; h < 2; ++h) {
            f16x8 af[4], bf[4];
#pragma unroll
            for (int i = 0; i < 4; ++i) {
                int r = wm * 64 + i * 16 + l16;
                af[i] = *(const f16x8*)&As[r * 64 + (((h * 4 + quad) ^ (r & 7)) * 8)];
                int c = wn * 64 + i * 16 + l16;
                bf[i] = *(const f16x8*)&Bs[c * 64 + (((h * 4 + quad) ^ (c & 7)) * 8)];
            }
#pragma unroll
            for (int i = 0; i < 4; ++i)
#pragma unroll
                for (int j = 0; j < 4; ++j)
                    acc[i][j] = __builtin_amdgcn_mfma_f32_16x16x32_f16(af[i], bf[j], acc[i][j], 0, 0, 0);
        }
        __syncthreads();   // all reads done before restage
    }

#pragma unroll
    for (int i = 0; i < 4; ++i) {
        int gr0 = row0 + wm * 64 + i * 16 + quad * 4;
#pragma unroll
        for (int r = 0; r < 4; ++r) {
            int grow = gr0 + r;
            if (grow >= M) continue;
#pragma unroll
            for (int j = 0; j < 4; ++j) {
                int gcol = col0 + wn * 64 + j * 16 + l16;
                float v = acc[i][j][r] + bias[gcol];
                if (RELU) v = fmaxf(v, 0.f);
                if (F16OUT) ((ushort*)Cout)[(size_t)grow * ldc + gcol] = f2h(v);
                else        ((float*)Cout)[(size_t)grow * ldc + gcol] = v;
            }
        }
    }
}

// --------------------------------------------------------------- attention (fp16, 2-edge ILP)
__global__ __launch_bounds__(256)
void attn_kernel(const ushort* __restrict__ C, const int* __restrict__ ssrc,
                 const int* __restrict__ estart, const int* __restrict__ ecnt,
                 ushort* __restrict__ attnhf) {
    int n = (blockIdx.x * 256 + threadIdx.x) >> 6;
    if (n >= N_NODES) return;
    int lane = threadIdx.x & 63;
    ushort2 qh = *(const ushort2*)&C[(size_t)n * 384 + 2 * lane];
    float qx = h2f(qh.x), qy = h2f(qh.y);
    int e0 = estart[n], e1 = e0 + ecnt[n];
    float wvx = 0.f, wvy = 0.f, z = 0.f;
    int e = e0;
    for (; e + 2 <= e1; e += 2) {
        int s0 = ssrc[e], s1 = ssrc[e + 1];
        ushort2 k0 = *(const ushort2*)&C[(size_t)s0 * 384 + 128 + 2 * lane];
        ushort2 k1 = *(const ushort2*)&C[(size_t)s1 * 384 + 128 + 2 * lane];
        ushort2 v0 = *(const ushort2*)&C[(size_t)s0 * 384 + 256 + 2 * lane];
        ushort2 v1 = *(const ushort2*)&C[(size_t)s1 * 384 + 256 + 2 * lane];
        float d0 = h2f(k0.x) * qx + h2f(k0.y) * qy;
        float d1 = h2f(k1.x) * qx + h2f(k1.y) * qy;
        d0 += __shfl_xor(d0, 1); d1 += __shfl_xor(d1, 1);
        d0 += __shfl_xor(d0, 2); d1 += __shfl_xor(d1, 2);
        d0 += __shfl_xor(d0, 4); d1 += __shfl_xor(d1, 4);
        float sc0 = __expf(fminf(fmaxf(d0 * 0.25f, -10.f), 10.f));
        float sc1 = __expf(fminf(fmaxf(d1 * 0.25f, -10.f), 10.f));
        wvx += sc0 * h2f(v0.x) + sc1 * h2f(v1.x);
        wvy += sc0 * h2f(v0.y) + sc1 * h2f(v1.y);
        z += sc0 + sc1;
    }
    if (e < e1) {
        int s = ssrc[e];
        ushort2 kh = *(const ushort2*)&C[(size_t)s * 384 + 128 + 2 * lane];
        float d = h2f(kh.x) * qx + h2f(kh.y) * qy;
        d += __shfl_xor(d, 1);
        d += __shfl_xor(d, 2);
        d += __shfl_xor(d, 4);
        float sc = __expf(fminf(fmaxf(d * 0.25f, -10.f), 10.f));
        ushort2 vh = *(const ushort2*)&C[(size_t)s * 384 + 256 + 2 * lane];
        wvx += sc * h2f(vh.x); wvy += sc * h2f(vh.y); z += sc;
    }
    float inv = 1.f / (z + 1e-6f);
    ushort2 o;
    o.x = f2h(wvx * inv);
    o.y = f2h(wvy * inv);
    *(ushort2*)&attnhf[(size_t)n * D + 2 * lane] = o;
}

// --------------------------------------------------------------- layernorm (fp32)
__global__ __launch_bounds__(256)
void ln_kernel(const float* __restrict__ x, const float* __restrict__ g,
               const float* __restrict__ b, float* __restrict__ out) {
    int n = (blockIdx.x * 256 + threadIdx.x) >> 6;
    if (n >= N_NODES) return;
    int lane = threadIdx.x & 63;
    float2 v = ((const float2*)&x[(size_t)n * D])[lane];
    float s = v.x + v.y;
#pragma unroll
    for (int off = 1; off < 64; off <<= 1) s += __shfl_xor(s, off);
    float mu = s * (1.f / 128.f);
    float dx = v.x - mu, dy = v.y - mu;
    float vs = dx * dx + dy * dy;
#pragma unroll
    for (int off = 1; off < 64; off <<= 1) vs += __shfl_xor(vs, off);
    float rstd = rsqrtf(vs * (1.f / 128.f) + 1e-5f);
    float2 gg = ((const float2*)g)[lane];
    float2 bb = ((const float2*)b)[lane];
    ((float2*)&out[(size_t)n * D])[lane] =
        make_float2(gg.x * dx * rstd + bb.x, gg.y * dy * rstd + bb.y);
}

// ------------------------------------------------------------------ launch
extern "C" void kernel_launch(void* const* d_in, const int* in_sizes, int n_in,
                              void* d_out, int out_size, void* d_ws, size_t ws_size,
                              hipStream_t stream) {
    (void)in_sizes; (void)n_in; (void)out_size;
    const float* h     = (const float*)d_in[0];
    const int*   src   = (const int*)d_in[1];
    const int*   dst   = (const int*)d_in[2];
    const int*   ety   = (const int*)d_in[3];
    const int*   seg   = (const int*)d_in[4];
    const float* coeffs[3] = {(const float*)d_in[6],  (const float*)d_in[10], (const float*)d_in[14]};
    const float* bases [3] = {(const float*)d_in[7],  (const float*)d_in[11], (const float*)d_in[15]};
    const float* loops [3] = {(const float*)d_in[8],  (const float*)d_in[12], (const float*)d_in[16]};
    const float* pbias [3] = {(const float*)d_in[9],  (const float*)d_in[13], (const float*)d_in[17]};
    const float* o_w   = (const float*)d_in[18];
    const float* o_b   = (const float*)d_in[19];
    const float* gn1_w = (const float*)d_in[20];
    const float* gn1_b = (const float*)d_in[21];
    const float* gn1_ms= (const float*)d_in[22];
    const float* gn2_w = (const float*)d_in[23];
    const float* gn2_b = (const float*)d_in[24];
    const float* gn2_ms= (const float*)d_in[25];
    const float* ln1_g = (const float*)d_in[26];
    const float* ln1_b = (const float*)d_in[27];
    const float* ln2_g = (const float*)d_in[28];
    const float* ln2_b = (const float*)d_in[29];
    const float* ffn1_w= (const float*)d_in[30];
    const float* ffn1_b= (const float*)d_in[31];
    const float* ffn2_w= (const float*)d_in[32];
    const float* ffn2_b= (const float*)d_in[33];

    char* p = (char*)d_ws;
    auto take = [&](size_t bytes) { char* r = p; p += (bytes + 255) & ~(size_t)255; return r; };
    int*    ecnt   = (int*)take((size_t)N_NODES * 4);
    int*    estart = (int*)take((size_t)N_NODES * 4);
    int*    ecur   = (int*)take((size_t)N_NODES * 4);
    int*    bsum   = (int*)take(512);
    int*    ssrc   = (int*)take((size_t)N_EDGES * 4);
    int*    setp   = (int*)take((size_t)N_EDGES * 4);
    float*  gsum   = (float*)take((size_t)NG * D * 4 * 2);
    float*  gsumsq = gsum + NG * D;
    float*  gsc    = (float*)take((size_t)NG * D * 4);
    float*  goff   = (float*)take((size_t)NG * D * 4);
    ushort* Btqkv  = (ushort*)take((size_t)384 * 1280 * 2);
    float*  biasq  = (float*)take(384 * 4);
    ushort* Bto    = (ushort*)take((size_t)128 * 128 * 2);
    ushort* Btf1   = (ushort*)take((size_t)256 * 128 * 2);
    ushort* Btf2   = (ushort*)take((size_t)128 * 256 * 2);
    ushort* hnhf   = (ushort*)take((size_t)N_NODES * D * 2);     // 25.6 MB
    ushort* attnhf = (ushort*)take((size_t)N_NODES * D * 2);     // 25.6 MB
    ushort* Cqkv   = (ushort*)take((size_t)N_NODES * 384 * 2);   // 76.8 MB
    float*  hO     = (float*)take((size_t)N_NODES * D * 4);      // 51.2 MB
    size_t used = (size_t)(p - (char*)d_ws);
    size_t avail = (ws_size > used) ? ws_size - used : 0;
    int NC = 1;
    if (avail < (size_t)N_NODES * 1280 * 2) NC = 4;
    if (NC == 4 && avail < ((size_t)(N_NODES / 4 + 1) * 1280 * 2)) NC = 8;
    ushort* Ab = (ushort*)p;
    const int chunk = (N_NODES + NC - 1) / NC;

    // dead-buffer aliases:
    ushort* gn2hf  = Cqkv;                                // Cqkv dead after attention
    ushort* ffn1hf = (ushort*)((char*)Cqkv + 25600000);
    float*  ffn2o  = (float*)hnhf;                        // hnhf+attnhf dead by FFN2

    const int EB = (N_EDGES + 255) / 256;
    const int SB = (N_NODES + 1023) / 1024;
    const int WB = (N_NODES * 64 + 255) / 256;
    const int GB = (N_NODES + 127) / 128;

    // ---- sort edges by dst
    hipMemsetAsync(ecnt, 0, N_NODES * sizeof(int), stream);
    hipMemsetAsync(ecur, 0, N_NODES * sizeof(int), stream);
    hist_kernel<<<EB, 256, 0, stream>>>(dst, ecnt);
    scan1_kernel<<<SB, 1024, 0, stream>>>(ecnt, estart, bsum, N_NODES);
    scan2_kernel<<<1, 128, 0, stream>>>(bsum, SB);
    scan3_kernel<<<SB, 1024, 0, stream>>>(estart, bsum, N_NODES);
    scatter_kernel<<<EB, 256, 0, stream>>>(src, dst, ety, estart, ecur, ssrc, setp);

    // ---- weights
    for (int pj = 0; pj < 3; ++pj)
        build_bt_qkv<<<640, 256, 0, stream>>>(coeffs[pj], bases[pj], loops[pj], pbias[pj],
                                              Btqkv + (size_t)pj * 128 * 1280, biasq + pj * 128);
    transpose_cast<<<64, 256, 0, stream>>>(o_w, 128, 128, Bto);
    transpose_cast<<<128, 256, 0, stream>>>(ffn1_w, 128, 256, Btf1);
    transpose_cast<<<128, 256, 0, stream>>>(ffn2_w, 256, 128, Btf2);

    // ---- graph norm 1 -> hnhf (fp16)
    hipMemsetAsync(gsum, 0, (size_t)NG * D * 8, stream);
    gn_stats<<<GB, 256, 0, stream>>>(h, seg, gsum, gsumsq);
    gn_final<<<NG, 128, 0, stream>>>(gsum, gsumsq, seg, gn1_w, gn1_b, gn1_ms, gsc, goff);
    gn_apply<<<WB, 256, 0, stream>>>(h, seg, gsc, goff, hnhf);

    // ---- QKV: S-pass + one big MFMA GEMM per chunk -> Cqkv (fp16)
    for (int c = 0; c < NC; ++c) {
        int c0 = c * chunk;
        int c1 = min(N_NODES, c0 + chunk);
        int rows = c1 - c0;
        if (rows <= 0) break;
        s_pass<<<(rows + 3) / 4, 256, 0, stream>>>(hnhf, ssrc, setp, estart, ecnt, Ab, c0, c1);
        mfma_gemm<true, true><<<dim3(3, (rows + 127) / 128), 256, 0, stream>>>(
            Ab, 1280, rows, Btqkv, 1280, biasq, Cqkv + (size_t)c0 * 384, 384);
    }

    // ---- attention -> attnhf (fp16); Cqkv dead after this
    attn_kernel<<<WB, 256, 0, stream>>>(Cqkv, ssrc, estart, ecnt, attnhf);

    // ---- output projection (fp32 out) + ln1 in-place
    mfma_gemm<false, false><<<dim3(1, (N_NODES + 127) / 128), 256, 0, stream>>>(
        attnhf, 128, N_NODES, Bto, 128, o_b, hO, 128);
    ln_kernel<<<WB, 256, 0, stream>>>(hO, ln1_g, ln1_b, hO);

    // ---- graph norm 2 -> gn2hf (fp16, dead Cqkv region)
    hipMemsetAsync(gsum, 0, (size_t)NG * D * 8, stream);
    gn_stats<<<GB, 256, 0, stream>>>(hO, seg, gsum, gsumsq);
    gn_final<<<NG, 128, 0, stream>>>(gsum, gsumsq, seg, gn2_w, gn2_b, gn2_ms, gsc, goff);
    gn_apply<<<WB, 256, 0, stream>>>(hO, seg, gsc, goff, gn2hf);

    // ---- FFN
    mfma_gemm<true, true><<<dim3(2, (N_NODES + 127) / 128), 256, 0, stream>>>(
        gn2hf, 128, N_NODES, Btf1, 128, ffn1_b, ffn1hf, 256);
    mfma_gemm<false, false><<<dim3(1, (N_NODES + 127) / 128), 256, 0, stream>>>(
        ffn1hf, 256, N_NODES, Btf2, 256, ffn2_b, ffn2o, 128);

    // ---- final layernorm -> d_out
    ln_kernel<<<WB, 256, 0, stream>>>(ffn2o, ln2_g, ln2_b, (float*)d_out);
}

// Round 5
// 803.276 us; speedup vs baseline: 5.0584x; 1.0605x over previous
//
#include <hip/hip_runtime.h>
#include <math.h>

#define N_NODES 100000
#define N_EDGES 600000
#define D 128
#define REL 9
#define NG 64

typedef float f32x4 __attribute__((ext_vector_type(4)));
typedef _Float16 f16x8 __attribute__((ext_vector_type(8)));

__device__ __forceinline__ ushort f2h(float x) {
    union { _Float16 h; ushort u; } c; c.h = (_Float16)x; return c.u;
}
__device__ __forceinline__ float h2f(ushort u) {
    union { ushort u; _Float16 h; } c; c.u = u; return (float)c.h;
}

// async global->LDS, 16 B per lane; dest = lds base (wave-uniform) + lane*16
__device__ __forceinline__ void ld16(const ushort* g, ushort* l) {
    __builtin_amdgcn_global_load_lds(
        (const __attribute__((address_space(1))) unsigned int*)g,
        (__attribute__((address_space(3))) unsigned int*)l, 16, 0, 0);
}

__device__ __forceinline__ int lbound(const int* __restrict__ a, int n, int key) {
    int lo = 0, hi = n;
    while (lo < hi) { int mid = (lo + hi) >> 1; if (a[mid] < key) lo = mid + 1; else hi = mid; }
    return lo;
}

// ------------------------------------------------------------ edge sorting
__global__ void hist_kernel(const int* __restrict__ dst, int* __restrict__ cnt) {
    int e = blockIdx.x * 256 + threadIdx.x;
    if (e < N_EDGES) atomicAdd(&cnt[dst[e]], 1);
}

__global__ void scan1_kernel(const int* __restrict__ cnt, int* __restrict__ excl,
                             int* __restrict__ bsum, int n) {
    __shared__ int s[1024];
    int tid = threadIdx.x;
    int i = blockIdx.x * 1024 + tid;
    int v = (i < n) ? cnt[i] : 0;
    s[tid] = v;
    __syncthreads();
    for (int off = 1; off < 1024; off <<= 1) {
        int t = (tid >= off) ? s[tid - off] : 0;
        __syncthreads();
        s[tid] += t;
        __syncthreads();
    }
    if (i < n) excl[i] = s[tid] - v;
    if (tid == 1023) bsum[blockIdx.x] = s[1023];
}

__global__ void scan2_kernel(int* __restrict__ bsum, int nb) {
    __shared__ int s[128];
    int tid = threadIdx.x;
    int v = (tid < nb) ? bsum[tid] : 0;
    s[tid] = v;
    __syncthreads();
    for (int off = 1; off < 128; off <<= 1) {
        int t = (tid >= off) ? s[tid - off] : 0;
        __syncthreads();
        s[tid] += t;
        __syncthreads();
    }
    if (tid < nb) bsum[tid] = s[tid] - v;
}

__global__ void scan3_kernel(int* __restrict__ excl, const int* __restrict__ bsum, int n) {
    int i = blockIdx.x * 1024 + threadIdx.x;
    if (i < n) excl[i] += bsum[blockIdx.x];
}

__global__ void scatter_kernel(const int* __restrict__ src, const int* __restrict__ dst,
                               const int* __restrict__ ety, const int* __restrict__ estart,
                               int* __restrict__ cur, int* __restrict__ ssrc,
                               int* __restrict__ setp) {
    int e = blockIdx.x * 256 + threadIdx.x;
    if (e < N_EDGES) {
        int d = dst[e];
        int pos = estart[d] + atomicAdd(&cur[d], 1);
        ssrc[pos] = src[e];
        setp[pos] = ety[e];
    }
}

// ------------------------------------------------------------- graph norm (moment form)
__global__ __launch_bounds__(256)
void gn_stats(const float* __restrict__ x, const int* __restrict__ seg,
              float* __restrict__ gsum, float* __restrict__ gsumsq) {
    int ch = threadIdx.x & 127;
    int rr = threadIdx.x >> 7;
    int n0 = blockIdx.x * 128;
    int nend = min(n0 + 128, N_NODES);
    float sx = 0.f, sxx = 0.f;
    int cg = -1;
    for (int n = n0 + rr; n < nend; n += 2) {
        int g = seg[n];
        if (g != cg) {
            if (cg >= 0) { atomicAdd(&gsum[cg * D + ch], sx); atomicAdd(&gsumsq[cg * D + ch], sxx); }
            cg = g; sx = 0.f; sxx = 0.f;
        }
        float v = x[(size_t)n * D + ch];
        sx += v; sxx += v * v;
    }
    if (cg >= 0) { atomicAdd(&gsum[cg * D + ch], sx); atomicAdd(&gsumsq[cg * D + ch], sxx); }
}

__global__ __launch_bounds__(256)
void gn_stats_h(const ushort* __restrict__ x, const int* __restrict__ seg,
                float* __restrict__ gsum, float* __restrict__ gsumsq) {
    int ch = threadIdx.x & 127;
    int rr = threadIdx.x >> 7;
    int n0 = blockIdx.x * 128;
    int nend = min(n0 + 128, N_NODES);
    float sx = 0.f, sxx = 0.f;
    int cg = -1;
    for (int n = n0 + rr; n < nend; n += 2) {
        int g = seg[n];
        if (g != cg) {
            if (cg >= 0) { atomicAdd(&gsum[cg * D + ch], sx); atomicAdd(&gsumsq[cg * D + ch], sxx); }
            cg = g; sx = 0.f; sxx = 0.f;
        }
        float v = h2f(x[(size_t)n * D + ch]);
        sx += v; sxx += v * v;
    }
    if (cg >= 0) { atomicAdd(&gsum[cg * D + ch], sx); atomicAdd(&gsumsq[cg * D + ch], sxx); }
}

__global__ void gn_final(const float* __restrict__ gsum, const float* __restrict__ gsumsq,
                         const int* __restrict__ seg, const float* __restrict__ w,
                         const float* __restrict__ b, const float* __restrict__ ms,
                         float* __restrict__ sc, float* __restrict__ off) {
    int g = blockIdx.x, ch = threadIdx.x;
    int lo = lbound(seg, N_NODES, g), hi = lbound(seg, N_NODES, g + 1);
    float cnt = (float)max(hi - lo, 1);
    float mean = gsum[g * D + ch] / cnt;
    float mm = mean * ms[ch];
    float var = gsumsq[g * D + ch] / cnt - 2.f * mm * mean + mm * mm;
    float rstd = rsqrtf(var + 1e-6f);
    float s = w[ch] * rstd;
    sc[g * D + ch] = s;
    off[g * D + ch] = b[ch] - s * mm;
}

__global__ __launch_bounds__(256)
void gn_apply(const float* __restrict__ x, const int* __restrict__ seg,
              const float* __restrict__ sc, const float* __restrict__ off,
              ushort* __restrict__ outhf) {
    int t = blockIdx.x * 256 + threadIdx.x;
    int n = t >> 6;
    if (n >= N_NODES) return;
    int ch = (t & 63) * 2;
    int g = seg[n];
    float2 xv = *(const float2*)&x[(size_t)n * D + ch];
    float2 s2 = *(const float2*)&sc[g * D + ch];
    float2 o2 = *(const float2*)&off[g * D + ch];
    ushort2 o;
    o.x = f2h(s2.x * xv.x + o2.x);
    o.y = f2h(s2.y * xv.y + o2.y);
    *(ushort2*)&outhf[(size_t)n * D + ch] = o;
}

__global__ __launch_bounds__(256)
void gn_apply_h(const ushort* __restrict__ x, const int* __restrict__ seg,
                const float* __restrict__ sc, const float* __restrict__ off,
                ushort* __restrict__ outhf) {
    int t = blockIdx.x * 256 + threadIdx.x;
    int n = t >> 6;
    if (n >= N_NODES) return;
    int ch = (t & 63) * 2;
    int g = seg[n];
    ushort2 xv = *(const ushort2*)&x[(size_t)n * D + ch];
    float2 s2 = *(const float2*)&sc[g * D + ch];
    float2 o2 = *(const float2*)&off[g * D + ch];
    ushort2 o;
    o.x = f2h(s2.x * h2f(xv.x) + o2.x);
    o.y = f2h(s2.y * h2f(xv.y) + o2.y);
    *(ushort2*)&outhf[(size_t)n * D + ch] = o;
}

// --------------------------------------------- combined QKV weight build (fp16, transposed)
__global__ void build_bt_qkv(const float* __restrict__ coeff, const float* __restrict__ basis,
                             const float* __restrict__ loop_w, const float* __restrict__ bias_in,
                             ushort* __restrict__ Bt, float* __restrict__ bias_out) {
    int t = blockIdx.x * 256 + threadIdx.x;
    if (t < 128) bias_out[t] = bias_in[t];
    if (t >= 128 * 1280) return;
    int o = t / 1280;
    int k = t - o * 1280;
    float v;
    if (k < 128) {
        v = loop_w[k * 128 + o];
    } else {
        int kk = k - 128;
        int r = kk >> 7, i = kk & 127;
        v = 0.f;
#pragma unroll
        for (int b = 0; b < REL; ++b)
            v += coeff[r * REL + b] * basis[((size_t)b * 128 + i) * 128 + o];
    }
    Bt[(size_t)o * 1280 + k] = f2h(v);
}

__global__ void transpose_cast(const float* __restrict__ W, int I, int O, ushort* __restrict__ Bt) {
    int t = blockIdx.x * 256 + threadIdx.x;
    if (t >= I * O) return;
    int n = t / I, k = t - n * I;
    Bt[(size_t)n * I + k] = f2h(W[(size_t)k * O + n]);
}

// ----------------------------------------- per-relation gathered sums -> S rows (fp16, 1152)
__global__ __launch_bounds__(256)
void s_pass(const ushort* __restrict__ hnhf, const int* __restrict__ ssrc,
            const int* __restrict__ setp, const int* __restrict__ estart,
            const int* __restrict__ ecnt, ushort* __restrict__ Ab, int c0, int c1) {
    int n = c0 + ((blockIdx.x * 256 + threadIdx.x) >> 6);
    if (n >= c1) return;
    int lane = threadIdx.x & 63;
    int e0 = estart[n], e1 = e0 + ecnt[n];
    float ax0=0,ay0=0,ax1=0,ay1=0,ax2=0,ay2=0,ax3=0,ay3=0,ax4=0,ay4=0;
    float ax5=0,ay5=0,ax6=0,ay6=0,ax7=0,ay7=0,ax8=0,ay8=0;
    for (int e = e0; e < e1; ++e) {
        int s = ssrc[e];
        int r = __builtin_amdgcn_readfirstlane(setp[e]);   // edge-uniform across the wave
        ushort2 hv = *(const ushort2*)&hnhf[(size_t)s * D + 2 * lane];
        float vx = h2f(hv.x), vy = h2f(hv.y);
        switch (r) {
            case 0: ax0 += vx; ay0 += vy; break;
            case 1: ax1 += vx; ay1 += vy; break;
            case 2: ax2 += vx; ay2 += vy; break;
            case 3: ax3 += vx; ay3 += vy; break;
            case 4: ax4 += vx; ay4 += vy; break;
            case 5: ax5 += vx; ay5 += vy; break;
            case 6: ax6 += vx; ay6 += vy; break;
            case 7: ax7 += vx; ay7 += vy; break;
            default: ax8 += vx; ay8 += vy; break;
        }
    }
    ushort* arow = Ab + (size_t)(n - c0) * 1152;
    ushort2 t;
#define ST(r) t.x = f2h(ax##r); t.y = f2h(ay##r); *(ushort2*)&arow[r * 128 + 2 * lane] = t;
    ST(0) ST(1) ST(2) ST(3) ST(4) ST(5) ST(6) ST(7) ST(8)
#undef ST
}

// ----------------------------------------------------------------- fp16 MFMA GEMM
// C[m][n] = sum_k A[m][k]*Bt[n][k] (+bias). m-tile 128, n-tile 128, k-step 64.
// SPLITA: k<128 read from A1 (lda 128), k>=128 from A2 (lda lda2, col k-128).
// LDS: 16-B chunk at slot (kg ^ (row&7)): lds-direct contiguous AND 2-way banks (free).
template<bool SPLITA, bool RELU, bool F16OUT>
__global__ __launch_bounds__(256, 3)
void mfma_gemm(const ushort* __restrict__ A1, const ushort* __restrict__ A2, int lda2, int M,
               const ushort* __restrict__ Bt, int K,
               const float* __restrict__ bias, void* __restrict__ Cout, int ldc) {
    __shared__ ushort As[128 * 64];
    __shared__ ushort Bs[128 * 64];
    const int tid = threadIdx.x;
    const int lane = tid & 63;
    const int wave = tid >> 6;
    const int wm = wave & 1, wn = wave >> 1;
    const int quad = lane >> 4, l16 = lane & 15;
    const int col0 = blockIdx.x * 128, row0 = blockIdx.y * 128;

    const ushort* sA1[4];
    const ushort* sA2[4];
    const ushort* sB[4];
#pragma unroll
    for (int i = 0; i < 4; ++i) {
        int rs = (wave * 4 + i) * 8 + (lane >> 3);
        int kg = (lane & 7) ^ (rs & 7);
        int ra = row0 + rs; if (ra >= M) ra = M - 1;
        sA1[i] = SPLITA ? (A1 + (size_t)ra * 128 + kg * 8) : nullptr;
        sA2[i] = A2 + (size_t)ra * lda2 + kg * 8;
        sB[i]  = Bt + (size_t)(col0 + rs) * K + kg * 8;
    }

    f32x4 acc[4][4];
#pragma unroll
    for (int i = 0; i < 4; ++i)
#pragma unroll
        for (int j = 0; j < 4; ++j) acc[i][j] = (f32x4){0.f, 0.f, 0.f, 0.f};

    for (int kc = 0; kc < K; kc += 64) {
#pragma unroll
        for (int i = 0; i < 4; ++i) {
            const ushort* as = (SPLITA && kc < 128) ? (sA1[i] + kc) : (sA2[i] + (SPLITA ? kc - 128 : kc));
            ld16(as, &As[(wave * 4 + i) * 512]);
            ld16(sB[i] + kc, &Bs[(wave * 4 + i) * 512]);
        }
        __syncthreads();
#pragma unroll
        for (int h = 0; h < 2; ++h) {
            f16x8 af[4], bf[4];
#pragma unroll
            for (int i = 0; i < 4; ++i) {
                int r = wm * 64 + i * 16 + l16;
                af[i] = *(const f16x8*)&As[r * 64 + (((h * 4 + quad) ^ (r & 7)) * 8)];
                int c = wn * 64 + i * 16 + l16;
                bf[i] = *(const f16x8*)&Bs[c * 64 + (((h * 4 + quad) ^ (c & 7)) * 8)];
            }
#pragma unroll
            for (int i = 0; i < 4; ++i)
#pragma unroll
                for (int j = 0; j < 4; ++j)
                    acc[i][j] = __builtin_amdgcn_mfma_f32_16x16x32_f16(af[i], bf[j], acc[i][j], 0, 0, 0);
        }
        __syncthreads();
    }

#pragma unroll
    for (int i = 0; i < 4; ++i) {
        int gr0 = row0 + wm * 64 + i * 16 + quad * 4;
#pragma unroll
        for (int r = 0; r < 4; ++r) {
            int grow = gr0 + r;
            if (grow >= M) continue;
#pragma unroll
            for (int j = 0; j < 4; ++j) {
                int gcol = col0 + wn * 64 + j * 16 + l16;
                float v = acc[i][j][r] + bias[gcol];
                if (RELU) v = fmaxf(v, 0.f);
                if (F16OUT) ((ushort*)Cout)[(size_t)grow * ldc + gcol] = f2h(v);
                else        ((float*)Cout)[(size_t)grow * ldc + gcol] = v;
            }
        }
    }
}

// ------------------------------------------------ fp16 MFMA GEMM + fused row LayerNorm
// N fixed 128 (single col block, full row per block). out = g*(v-mu)*rstd + b.
template<bool F16OUT>
__global__ __launch_bounds__(256, 3)
void mfma_gemm_ln(const ushort* __restrict__ A, int lda, int M,
                  const ushort* __restrict__ Bt, int K,
                  const float* __restrict__ bias, const float* __restrict__ lng,
                  const float* __restrict__ lnb, void* __restrict__ Cout) {
    __shared__ ushort As[128 * 64];
    __shared__ ushort Bs[128 * 64];
    __shared__ float rsum[2][128];
    __shared__ float rsq[2][128];
    const int tid = threadIdx.x;
    const int lane = tid & 63;
    const int wave = tid >> 6;
    const int wm = wave & 1, wn = wave >> 1;
    const int quad = lane >> 4, l16 = lane & 15;
    const int row0 = blockIdx.y * 128;

    const ushort* sA[4];
    const ushort* sB[4];
#pragma unroll
    for (int i = 0; i < 4; ++i) {
        int rs = (wave * 4 + i) * 8 + (lane >> 3);
        int kg = (lane & 7) ^ (rs & 7);
        int ra = row0 + rs; if (ra >= M) ra = M - 1;
        sA[i] = A + (size_t)ra * lda + kg * 8;
        sB[i] = Bt + (size_t)rs * K + kg * 8;   // col0 == 0
    }

    f32x4 acc[4][4];
#pragma unroll
    for (int i = 0; i < 4; ++i)
#pragma unroll
        for (int j = 0; j < 4; ++j) acc[i][j] = (f32x4){0.f, 0.f, 0.f, 0.f};

    for (int kc = 0; kc < K; kc += 64) {
#pragma unroll
        for (int i = 0; i < 4; ++i) {
            ld16(sA[i] + kc, &As[(wave * 4 + i) * 512]);
            ld16(sB[i] + kc, &Bs[(wave * 4 + i) * 512]);
        }
        __syncthreads();
#pragma unroll
        for (int h = 0; h < 2; ++h) {
            f16x8 af[4], bf[4];
#pragma unroll
            for (int i = 0; i < 4; ++i) {
                int r = wm * 64 + i * 16 + l16;
                af[i] = *(const f16x8*)&As[r * 64 + (((h * 4 + quad) ^ (r & 7)) * 8)];
                int c = wn * 64 + i * 16 + l16;
                bf[i] = *(const f16x8*)&Bs[c * 64 + (((h * 4 + quad) ^ (c & 7)) * 8)];
            }
#pragma unroll
            for (int i = 0; i < 4; ++i)
#pragma unroll
                for (int j = 0; j < 4; ++j)
                    acc[i][j] = __builtin_amdgcn_mfma_f32_16x16x32_f16(af[i], bf[j], acc[i][j], 0, 0, 0);
        }
        __syncthreads();
    }

    // per-row partial sums across this wave's 64 cols, butterfly over l16
#pragma unroll
    for (int i = 0; i < 4; ++i) {
#pragma unroll
        for (int r = 0; r < 4; ++r) {
            float s = 0.f, q = 0.f;
#pragma unroll
            for (int j = 0; j < 4; ++j) {
                float v = acc[i][j][r] + bias[wn * 64 + j * 16 + l16];
                s += v; q += v * v;
            }
            s += __shfl_xor(s, 1); q += __shfl_xor(q, 1);
            s += __shfl_xor(s, 2); q += __shfl_xor(q, 2);
            s += __shfl_xor(s, 4); q += __shfl_xor(q, 4);
            s += __shfl_xor(s, 8); q += __shfl_xor(q, 8);
            if (l16 == 0) {
                int row = wm * 64 + i * 16 + quad * 4 + r;
                rsum[wn][row] = s;
                rsq[wn][row] = q;
            }
        }
    }
    __syncthreads();

#pragma unroll
    for (int i = 0; i < 4; ++i) {
#pragma unroll
        for (int r = 0; r < 4; ++r) {
            int row = wm * 64 + i * 16 + quad * 4 + r;
            int grow = row0 + row;
            if (grow >= M) continue;
            float tot = rsum[0][row] + rsum[1][row];
            float tq  = rsq[0][row] + rsq[1][row];
            float mu = tot * (1.f / 128.f);
            float var = tq * (1.f / 128.f) - mu * mu;
            float rstd = rsqrtf(var + 1e-5f);
#pragma unroll
            for (int j = 0; j < 4; ++j) {
                int gcol = wn * 64 + j * 16 + l16;
                float v = acc[i][j][r] + bias[gcol];
                float o = lng[gcol] * (v - mu) * rstd + lnb[gcol];
                if (F16OUT) ((ushort*)Cout)[(size_t)grow * 128 + gcol] = f2h(o);
                else        ((float*)Cout)[(size_t)grow * 128 + gcol] = o;
            }
        }
    }
}

// --------------------------------------------------------------- attention (merged K|V gather)
// lane l loads ushort4 at C[s*384+128+4l]: l<32 -> K chans 4l..4l+3, l>=32 -> V chans 4(l-32)..
__global__ __launch_bounds__(256)
void attn_kernel(const ushort* __restrict__ C, const int* __restrict__ ssrc,
                 const int* __restrict__ estart, const int* __restrict__ ecnt,
                 ushort* __restrict__ attnhf) {
    int n = (blockIdx.x * 256 + threadIdx.x) >> 6;
    if (n >= N_NODES) return;
    int lane = threadIdx.x & 63;
    ushort4 qh = *(const ushort4*)&C[(size_t)n * 384 + 4 * (lane & 31)];
    float q0 = h2f(qh.x), q1 = h2f(qh.y), q2 = h2f(qh.z), q3 = h2f(qh.w);
    int e0 = estart[n], e1 = e0 + ecnt[n];
    float w0 = 0.f, w1 = 0.f, w2 = 0.f, w3 = 0.f, z = 0.f;
    const bool isK = lane < 32;
    int e = e0;
    for (; e + 2 <= e1; e += 2) {
        int s0 = ssrc[e], s1 = ssrc[e + 1];
        ushort4 a = *(const ushort4*)&C[(size_t)s0 * 384 + 128 + 4 * lane];
        ushort4 b = *(const ushort4*)&C[(size_t)s1 * 384 + 128 + 4 * lane];
        float d0 = h2f(a.x) * q0 + h2f(a.y) * q1 + h2f(a.z) * q2 + h2f(a.w) * q3;
        float d1 = h2f(b.x) * q0 + h2f(b.y) * q1 + h2f(b.z) * q2 + h2f(b.w) * q3;
        d0 += __shfl_xor(d0, 1); d1 += __shfl_xor(d1, 1);
        d0 += __shfl_xor(d0, 2); d1 += __shfl_xor(d1, 2);
        float p0 = __shfl_xor(d0, 32), p1 = __shfl_xor(d1, 32);
        d0 = isK ? d0 : p0; d1 = isK ? d1 : p1;
        float sc0 = __expf(fminf(fmaxf(d0 * 0.25f, -10.f), 10.f));
        float sc1 = __expf(fminf(fmaxf(d1 * 0.25f, -10.f), 10.f));
        w0 += sc0 * h2f(a.x) + sc1 * h2f(b.x);
        w1 += sc0 * h2f(a.y) + sc1 * h2f(b.y);
        w2 += sc0 * h2f(a.z) + sc1 * h2f(b.z);
        w3 += sc0 * h2f(a.w) + sc1 * h2f(b.w);
        z += sc0 + sc1;
    }
    if (e < e1) {
        int s0 = ssrc[e];
        ushort4 a = *(const ushort4*)&C[(size_t)s0 * 384 + 128 + 4 * lane];
        float d0 = h2f(a.x) * q0 + h2f(a.y) * q1 + h2f(a.z) * q2 + h2f(a.w) * q3;
        d0 += __shfl_xor(d0, 1);
        d0 += __shfl_xor(d0, 2);
        float p0 = __shfl_xor(d0, 32);
        d0 = isK ? d0 : p0;
        float sc0 = __expf(fminf(fmaxf(d0 * 0.25f, -10.f), 10.f));
        w0 += sc0 * h2f(a.x); w1 += sc0 * h2f(a.y);
        w2 += sc0 * h2f(a.z); w3 += sc0 * h2f(a.w);
        z += sc0;
    }
    if (!isK) {
        float inv = 1.f / (z + 1e-6f);
        ushort4 o;
        o.x = f2h(w0 * inv); o.y = f2h(w1 * inv);
        o.z = f2h(w2 * inv); o.w = f2h(w3 * inv);
        *(ushort4*)&attnhf[(size_t)n * D + 4 * (lane - 32)] = o;
    }
}

// ------------------------------------------------------------------ launch
extern "C" void kernel_launch(void* const* d_in, const int* in_sizes, int n_in,
                              void* d_out, int out_size, void* d_ws, size_t ws_size,
                              hipStream_t stream) {
    (void)in_sizes; (void)n_in; (void)out_size;
    const float* h     = (const float*)d_in[0];
    const int*   src   = (const int*)d_in[1];
    const int*   dst   = (const int*)d_in[2];
    const int*   ety   = (const int*)d_in[3];
    const int*   seg   = (const int*)d_in[4];
    const float* coeffs[3] = {(const float*)d_in[6],  (const float*)d_in[10], (const float*)d_in[14]};
    const float* bases [3] = {(const float*)d_in[7],  (const float*)d_in[11], (const float*)d_in[15]};
    const float* loops [3] = {(const float*)d_in[8],  (const float*)d_in[12], (const float*)d_in[16]};
    const float* pbias [3] = {(const float*)d_in[9],  (const float*)d_in[13], (const float*)d_in[17]};
    const float* o_w   = (const float*)d_in[18];
    const float* o_b   = (const float*)d_in[19];
    const float* gn1_w = (const float*)d_in[20];
    const float* gn1_b = (const float*)d_in[21];
    const float* gn1_ms= (const float*)d_in[22];
    const float* gn2_w = (const float*)d_in[23];
    const float* gn2_b = (const float*)d_in[24];
    const float* gn2_ms= (const float*)d_in[25];
    const float* ln1_g = (const float*)d_in[26];
    const float* ln1_b = (const float*)d_in[27];
    const float* ln2_g = (const float*)d_in[28];
    const float* ln2_b = (const float*)d_in[29];
    const float* ffn1_w= (const float*)d_in[30];
    const float* ffn1_b= (const float*)d_in[31];
    const float* ffn2_w= (const float*)d_in[32];
    const float* ffn2_b= (const float*)d_in[33];

    char* p = (char*)d_ws;
    auto take = [&](size_t bytes) { char* r = p; p += (bytes + 255) & ~(size_t)255; return r; };
    int*    ecnt   = (int*)take((size_t)N_NODES * 4);
    int*    estart = (int*)take((size_t)N_NODES * 4);
    int*    ecur   = (int*)take((size_t)N_NODES * 4);
    int*    bsum   = (int*)take(512);
    int*    ssrc   = (int*)take((size_t)N_EDGES * 4);
    int*    setp   = (int*)take((size_t)N_EDGES * 4);
    float*  gsum   = (float*)take((size_t)NG * D * 4 * 2);
    float*  gsumsq = gsum + NG * D;
    float*  gsc    = (float*)take((size_t)NG * D * 4);
    float*  goff   = (float*)take((size_t)NG * D * 4);
    ushort* Btqkv  = (ushort*)take((size_t)384 * 1280 * 2);
    float*  biasq  = (float*)take(384 * 4);
    ushort* Bto    = (ushort*)take((size_t)128 * 128 * 2);
    ushort* Btf1   = (ushort*)take((size_t)256 * 128 * 2);
    ushort* Btf2   = (ushort*)take((size_t)128 * 256 * 2);
    ushort* hnhf   = (ushort*)take((size_t)N_NODES * D * 2);     // 25.6 MB
    ushort* attnhf = (ushort*)take((size_t)N_NODES * D * 2);     // 25.6 MB
    ushort* h1hf   = (ushort*)take((size_t)N_NODES * D * 2);     // 25.6 MB
    ushort* Cqkv   = (ushort*)take((size_t)N_NODES * 384 * 2);   // 76.8 MB
    size_t used = (size_t)(p - (char*)d_ws);
    size_t avail = (ws_size > used) ? ws_size - used : 0;
    int NC = 1;
    if (avail < (size_t)N_NODES * 1152 * 2) NC = 4;
    if (NC == 4 && avail < ((size_t)(N_NODES / 4 + 1) * 1152 * 2)) NC = 8;
    ushort* Ab = (ushort*)p;
    const int chunk = (N_NODES + NC - 1) / NC;

    // dead-buffer aliases: Cqkv dead after attention; holds gn2hf (25.6) + ffn1hf (51.2)
    ushort* gn2hf  = Cqkv;
    ushort* ffn1hf = (ushort*)((char*)Cqkv + 25600000);

    const int EB = (N_EDGES + 255) / 256;
    const int SB = (N_NODES + 1023) / 1024;
    const int WB = (N_NODES * 64 + 255) / 256;
    const int GB = (N_NODES + 127) / 128;
    const int RB = (N_NODES + 127) / 128;

    // ---- sort edges by dst
    hipMemsetAsync(ecnt, 0, N_NODES * sizeof(int), stream);
    hipMemsetAsync(ecur, 0, N_NODES * sizeof(int), stream);
    hist_kernel<<<EB, 256, 0, stream>>>(dst, ecnt);
    scan1_kernel<<<SB, 1024, 0, stream>>>(ecnt, estart, bsum, N_NODES);
    scan2_kernel<<<1, 128, 0, stream>>>(bsum, SB);
    scan3_kernel<<<SB, 1024, 0, stream>>>(estart, bsum, N_NODES);
    scatter_kernel<<<EB, 256, 0, stream>>>(src, dst, ety, estart, ecur, ssrc, setp);

    // ---- weights
    for (int pj = 0; pj < 3; ++pj)
        build_bt_qkv<<<640, 256, 0, stream>>>(coeffs[pj], bases[pj], loops[pj], pbias[pj],
                                              Btqkv + (size_t)pj * 128 * 1280, biasq + pj * 128);
    transpose_cast<<<64, 256, 0, stream>>>(o_w, 128, 128, Bto);
    transpose_cast<<<128, 256, 0, stream>>>(ffn1_w, 128, 256, Btf1);
    transpose_cast<<<128, 256, 0, stream>>>(ffn2_w, 256, 128, Btf2);

    // ---- graph norm 1 -> hnhf (fp16)
    hipMemsetAsync(gsum, 0, (size_t)NG * D * 8, stream);
    gn_stats<<<GB, 256, 0, stream>>>(h, seg, gsum, gsumsq);
    gn_final<<<NG, 128, 0, stream>>>(gsum, gsumsq, seg, gn1_w, gn1_b, gn1_ms, gsc, goff);
    gn_apply<<<WB, 256, 0, stream>>>(h, seg, gsc, goff, hnhf);

    // ---- QKV: S-pass + split-A MFMA GEMM per chunk -> Cqkv (fp16)
    for (int c = 0; c < NC; ++c) {
        int c0 = c * chunk;
        int c1 = min(N_NODES, c0 + chunk);
        int rows = c1 - c0;
        if (rows <= 0) break;
        s_pass<<<(rows + 3) / 4, 256, 0, stream>>>(hnhf, ssrc, setp, estart, ecnt, Ab, c0, c1);
        mfma_gemm<true, true, true><<<dim3(3, (rows + 127) / 128), 256, 0, stream>>>(
            hnhf + (size_t)c0 * 128, Ab, 1152, rows, Btqkv, 1280, biasq,
            Cqkv + (size_t)c0 * 384, 384);
    }

    // ---- attention -> attnhf (fp16); Cqkv dead after this
    attn_kernel<<<WB, 256, 0, stream>>>(Cqkv, ssrc, estart, ecnt, attnhf);

    // ---- output projection + fused ln1 -> h1hf (fp16)
    mfma_gemm_ln<true><<<dim3(1, RB), 256, 0, stream>>>(
        attnhf, 128, N_NODES, Bto, 128, o_b, ln1_g, ln1_b, h1hf);

    // ---- graph norm 2 (fp16 path) -> gn2hf
    hipMemsetAsync(gsum, 0, (size_t)NG * D * 8, stream);
    gn_stats_h<<<GB, 256, 0, stream>>>(h1hf, seg, gsum, gsumsq);
    gn_final<<<NG, 128, 0, stream>>>(gsum, gsumsq, seg, gn2_w, gn2_b, gn2_ms, gsc, goff);
    gn_apply_h<<<WB, 256, 0, stream>>>(h1hf, seg, gsc, goff, gn2hf);

    // ---- FFN: ffn1 (relu, fp16) then ffn2 + fused ln2 -> d_out (fp32)
    mfma_gemm<false, true, true><<<dim3(2, RB), 256, 0, stream>>>(
        nullptr, gn2hf, 128, N_NODES, Btf1, 128, ffn1_b, ffn1hf, 256);
    mfma_gemm_ln<false><<<dim3(1, RB), 256, 0, stream>>>(
        ffn1hf, 256, N_NODES, Btf2, 256, ffn2_b, ln2_g, ln2_b, (float*)d_out);
}

// Round 6
// 767.463 us; speedup vs baseline: 5.2945x; 1.0467x over previous
//
#include <hip/hip_runtime.h>
#include <math.h>

#define N_NODES 100000
#define N_EDGES 600000
#define D 128
#define REL 9
#define NG 64

typedef float f32x4 __attribute__((ext_vector_type(4)));
typedef _Float16 f16x8 __attribute__((ext_vector_type(8)));
typedef _Float16 h16x2 __attribute__((ext_vector_type(2)));

__device__ __forceinline__ ushort f2h(float x) {
    union { _Float16 h; ushort u; } c; c.h = (_Float16)x; return c.u;
}
__device__ __forceinline__ float h2f(ushort u) {
    union { ushort u; _Float16 h; } c; c.u = u; return (float)c.h;
}

// async global->LDS, 16 B per lane; dest = lds base (wave-uniform) + lane*16
__device__ __forceinline__ void ld16(const ushort* g, ushort* l) {
    __builtin_amdgcn_global_load_lds(
        (const __attribute__((address_space(1))) unsigned int*)g,
        (__attribute__((address_space(3))) unsigned int*)l, 16, 0, 0);
}

__device__ __forceinline__ int lbound(const int* __restrict__ a, int n, int key) {
    int lo = 0, hi = n;
    while (lo < hi) { int mid = (lo + hi) >> 1; if (a[mid] < key) lo = mid + 1; else hi = mid; }
    return lo;
}

// ------------------------------------------------------------ edge sorting
__global__ void hist_kernel(const int* __restrict__ dst, int* __restrict__ cnt) {
    int e = blockIdx.x * 256 + threadIdx.x;
    if (e < N_EDGES) atomicAdd(&cnt[dst[e]], 1);
}

__global__ void scan1_kernel(const int* __restrict__ cnt, int* __restrict__ excl,
                             int* __restrict__ bsum, int n) {
    __shared__ int s[1024];
    int tid = threadIdx.x;
    int i = blockIdx.x * 1024 + tid;
    int v = (i < n) ? cnt[i] : 0;
    s[tid] = v;
    __syncthreads();
    for (int off = 1; off < 1024; off <<= 1) {
        int t = (tid >= off) ? s[tid - off] : 0;
        __syncthreads();
        s[tid] += t;
        __syncthreads();
    }
    if (i < n) excl[i] = s[tid] - v;
    if (tid == 1023) bsum[blockIdx.x] = s[1023];
}

__global__ void scan2_kernel(int* __restrict__ bsum, int nb) {
    __shared__ int s[128];
    int tid = threadIdx.x;
    int v = (tid < nb) ? bsum[tid] : 0;
    s[tid] = v;
    __syncthreads();
    for (int off = 1; off < 128; off <<= 1) {
        int t = (tid >= off) ? s[tid - off] : 0;
        __syncthreads();
        s[tid] += t;
        __syncthreads();
    }
    if (tid < nb) bsum[tid] = s[tid] - v;
}

__global__ void scan3_kernel(int* __restrict__ excl, const int* __restrict__ bsum, int n) {
    int i = blockIdx.x * 1024 + threadIdx.x;
    if (i < n) excl[i] += bsum[blockIdx.x];
}

__global__ void scatter_kernel(const int* __restrict__ src, const int* __restrict__ dst,
                               const int* __restrict__ ety, const int* __restrict__ estart,
                               int* __restrict__ cur, int* __restrict__ ssrc,
                               int* __restrict__ setp) {
    int e = blockIdx.x * 256 + threadIdx.x;
    if (e < N_EDGES) {
        int d = dst[e];
        int pos = estart[d] + atomicAdd(&cur[d], 1);
        ssrc[pos] = src[e];
        setp[pos] = ety[e];
    }
}

// ------------------------------------------------------------- graph norm (moment form)
__global__ __launch_bounds__(256)
void gn_stats(const float* __restrict__ x, const int* __restrict__ seg,
              float* __restrict__ gsum, float* __restrict__ gsumsq) {
    int ch = threadIdx.x & 127;
    int rr = threadIdx.x >> 7;
    int n0 = blockIdx.x * 128;
    int nend = min(n0 + 128, N_NODES);
    float sx = 0.f, sxx = 0.f;
    int cg = -1;
    for (int n = n0 + rr; n < nend; n += 2) {
        int g = seg[n];
        if (g != cg) {
            if (cg >= 0) { atomicAdd(&gsum[cg * D + ch], sx); atomicAdd(&gsumsq[cg * D + ch], sxx); }
            cg = g; sx = 0.f; sxx = 0.f;
        }
        float v = x[(size_t)n * D + ch];
        sx += v; sxx += v * v;
    }
    if (cg >= 0) { atomicAdd(&gsum[cg * D + ch], sx); atomicAdd(&gsumsq[cg * D + ch], sxx); }
}

__global__ __launch_bounds__(256)
void gn_stats_h(const ushort* __restrict__ x, const int* __restrict__ seg,
                float* __restrict__ gsum, float* __restrict__ gsumsq) {
    int ch = threadIdx.x & 127;
    int rr = threadIdx.x >> 7;
    int n0 = blockIdx.x * 128;
    int nend = min(n0 + 128, N_NODES);
    float sx = 0.f, sxx = 0.f;
    int cg = -1;
    for (int n = n0 + rr; n < nend; n += 2) {
        int g = seg[n];
        if (g != cg) {
            if (cg >= 0) { atomicAdd(&gsum[cg * D + ch], sx); atomicAdd(&gsumsq[cg * D + ch], sxx); }
            cg = g; sx = 0.f; sxx = 0.f;
        }
        float v = h2f(x[(size_t)n * D + ch]);
        sx += v; sxx += v * v;
    }
    if (cg >= 0) { atomicAdd(&gsum[cg * D + ch], sx); atomicAdd(&gsumsq[cg * D + ch], sxx); }
}

__global__ void gn_final(const float* __restrict__ gsum, const float* __restrict__ gsumsq,
                         const int* __restrict__ seg, const float* __restrict__ w,
                         const float* __restrict__ b, const float* __restrict__ ms,
                         float* __restrict__ sc, float* __restrict__ off) {
    int g = blockIdx.x, ch = threadIdx.x;
    int lo = lbound(seg, N_NODES, g), hi = lbound(seg, N_NODES, g + 1);
    float cnt = (float)max(hi - lo, 1);
    float mean = gsum[g * D + ch] / cnt;
    float mm = mean * ms[ch];
    float var = gsumsq[g * D + ch] / cnt - 2.f * mm * mean + mm * mm;
    float rstd = rsqrtf(var + 1e-6f);
    float s = w[ch] * rstd;
    sc[g * D + ch] = s;
    off[g * D + ch] = b[ch] - s * mm;
}

__global__ __launch_bounds__(256)
void gn_apply(const float* __restrict__ x, const int* __restrict__ seg,
              const float* __restrict__ sc, const float* __restrict__ off,
              ushort* __restrict__ outhf) {
    int t = blockIdx.x * 256 + threadIdx.x;
    int n = t >> 6;
    if (n >= N_NODES) return;
    int ch = (t & 63) * 2;
    int g = seg[n];
    float2 xv = *(const float2*)&x[(size_t)n * D + ch];
    float2 s2 = *(const float2*)&sc[g * D + ch];
    float2 o2 = *(const float2*)&off[g * D + ch];
    ushort2 o;
    o.x = f2h(s2.x * xv.x + o2.x);
    o.y = f2h(s2.y * xv.y + o2.y);
    *(ushort2*)&outhf[(size_t)n * D + ch] = o;
}

__global__ __launch_bounds__(256)
void gn_apply_h(const ushort* __restrict__ x, const int* __restrict__ seg,
                const float* __restrict__ sc, const float* __restrict__ off,
                ushort* __restrict__ outhf) {
    int t = blockIdx.x * 256 + threadIdx.x;
    int n = t >> 6;
    if (n >= N_NODES) return;
    int ch = (t & 63) * 2;
    int g = seg[n];
    ushort2 xv = *(const ushort2*)&x[(size_t)n * D + ch];
    float2 s2 = *(const float2*)&sc[g * D + ch];
    float2 o2 = *(const float2*)&off[g * D + ch];
    ushort2 o;
    o.x = f2h(s2.x * h2f(xv.x) + o2.x);
    o.y = f2h(s2.y * h2f(xv.y) + o2.y);
    *(ushort2*)&outhf[(size_t)n * D + ch] = o;
}

// ------------------------- combined QKV weight build (fp16, transposed), all 3 projections
__global__ void build_bt_qkv3(const float* __restrict__ c0, const float* __restrict__ c1,
                              const float* __restrict__ c2, const float* __restrict__ b0,
                              const float* __restrict__ b1, const float* __restrict__ b2,
                              const float* __restrict__ l0, const float* __restrict__ l1,
                              const float* __restrict__ l2, const float* __restrict__ i0,
                              const float* __restrict__ i1, const float* __restrict__ i2,
                              ushort* __restrict__ Btqkv, float* __restrict__ biasq) {
    int pj = blockIdx.y;
    const float* coeff  = pj == 0 ? c0 : (pj == 1 ? c1 : c2);
    const float* basis  = pj == 0 ? b0 : (pj == 1 ? b1 : b2);
    const float* loop_w = pj == 0 ? l0 : (pj == 1 ? l1 : l2);
    const float* bin    = pj == 0 ? i0 : (pj == 1 ? i1 : i2);
    ushort* Bt = Btqkv + (size_t)pj * 128 * 1280;
    int t = blockIdx.x * 256 + threadIdx.x;
    if (t < 128) biasq[pj * 128 + t] = bin[t];
    if (t >= 128 * 1280) return;
    int o = t / 1280;
    int k = t - o * 1280;
    float v;
    if (k < 128) {
        v = loop_w[k * 128 + o];
    } else {
        int kk = k - 128;
        int r = kk >> 7, i = kk & 127;
        v = 0.f;
#pragma unroll
        for (int b = 0; b < REL; ++b)
            v += coeff[r * REL + b] * basis[((size_t)b * 128 + i) * 128 + o];
    }
    Bt[(size_t)o * 1280 + k] = f2h(v);
}

// single launch for o_w / ffn1 / ffn2 transposed fp16 weights
__global__ void transpose_cast3(const float* __restrict__ o_w, ushort* __restrict__ Bto,
                                const float* __restrict__ f1, ushort* __restrict__ Btf1,
                                const float* __restrict__ f2, ushort* __restrict__ Btf2) {
    int t = blockIdx.x * 256 + threadIdx.x;
    if (t < 16384) {                 // o_w: I=128, O=128
        int n = t >> 7, k = t & 127;
        Bto[(size_t)n * 128 + k] = f2h(o_w[(size_t)k * 128 + n]);
    } else if (t < 49152) {          // ffn1: I=128, O=256
        int u = t - 16384;
        int n = u >> 7, k = u & 127;
        Btf1[(size_t)n * 128 + k] = f2h(f1[(size_t)k * 256 + n]);
    } else if (t < 81920) {          // ffn2: I=256, O=128
        int u = t - 49152;
        int n = u >> 8, k = u & 255;
        Btf2[(size_t)n * 256 + k] = f2h(f2[(size_t)k * 128 + n]);
    }
}

// ----------------------------------------- per-relation gathered sums -> S rows (fp16, 1152)
// half2 packed accumulation (v_pk_add_f16); |S| <= ~50, safe in fp16.
__global__ __launch_bounds__(256)
void s_pass(const ushort* __restrict__ hnhf, const int* __restrict__ ssrc,
            const int* __restrict__ setp, const int* __restrict__ estart,
            const int* __restrict__ ecnt, ushort* __restrict__ Ab, int c0, int c1) {
    int n = c0 + ((blockIdx.x * 256 + threadIdx.x) >> 6);
    if (n >= c1) return;
    int lane = threadIdx.x & 63;
    int e0 = estart[n], e1 = e0 + ecnt[n];
    h16x2 a0 = (h16x2)0, a1 = (h16x2)0, a2 = (h16x2)0, a3 = (h16x2)0, a4 = (h16x2)0;
    h16x2 a5 = (h16x2)0, a6 = (h16x2)0, a7 = (h16x2)0, a8 = (h16x2)0;
#define ACC(rr, hv) switch (rr) { \
        case 0: a0 += hv; break; case 1: a1 += hv; break; case 2: a2 += hv; break; \
        case 3: a3 += hv; break; case 4: a4 += hv; break; case 5: a5 += hv; break; \
        case 6: a6 += hv; break; case 7: a7 += hv; break; default: a8 += hv; break; }
    int e = e0;
    for (; e + 2 <= e1; e += 2) {
        int s0 = ssrc[e], s1 = ssrc[e + 1];
        int r0 = __builtin_amdgcn_readfirstlane(setp[e]);
        int r1 = __builtin_amdgcn_readfirstlane(setp[e + 1]);
        h16x2 hv0 = *(const h16x2*)&hnhf[(size_t)s0 * D + 2 * lane];
        h16x2 hv1 = *(const h16x2*)&hnhf[(size_t)s1 * D + 2 * lane];
        ACC(r0, hv0)
        ACC(r1, hv1)
    }
    if (e < e1) {
        int s0 = ssrc[e];
        int r0 = __builtin_amdgcn_readfirstlane(setp[e]);
        h16x2 hv0 = *(const h16x2*)&hnhf[(size_t)s0 * D + 2 * lane];
        ACC(r0, hv0)
    }
#undef ACC
    ushort* arow = Ab + (size_t)(n - c0) * 1152;
#define ST(r) *(h16x2*)&arow[r * 128 + 2 * lane] = a##r;
    ST(0) ST(1) ST(2) ST(3) ST(4) ST(5) ST(6) ST(7) ST(8)
#undef ST
}

// ----------------------------------------------------------------- fp16 MFMA GEMM
// C[m][n] = sum_k A[m][k]*Bt[n][k] (+bias). m-tile 128, n-tile 128, k-step 64.
// SPLITA: k<128 read from A1 (lda 128), k>=128 from A2 (lda lda2, col k-128).
// LDS: 16-B chunk at slot (kg ^ (row&7)): lds-direct contiguous AND 2-way banks (free).
template<bool SPLITA, bool RELU, bool F16OUT>
__global__ __launch_bounds__(256, 3)
void mfma_gemm(const ushort* __restrict__ A1, const ushort* __restrict__ A2, int lda2, int M,
               const ushort* __restrict__ Bt, int K,
               const float* __restrict__ bias, void* __restrict__ Cout, int ldc) {
    __shared__ ushort As[128 * 64];
    __shared__ ushort Bs[128 * 64];
    const int tid = threadIdx.x;
    const int lane = tid & 63;
    const int wave = tid >> 6;
    const int wm = wave & 1, wn = wave >> 1;
    const int quad = lane >> 4, l16 = lane & 15;
    const int col0 = blockIdx.x * 128, row0 = blockIdx.y * 128;

    const ushort* sA1[4];
    const ushort* sA2[4];
    const ushort* sB[4];
#pragma unroll
    for (int i = 0; i < 4; ++i) {
        int rs = (wave * 4 + i) * 8 + (lane >> 3);
        int kg = (lane & 7) ^ (rs & 7);
        int ra = row0 + rs; if (ra >= M) ra = M - 1;
        sA1[i] = SPLITA ? (A1 + (size_t)ra * 128 + kg * 8) : nullptr;
        sA2[i] = A2 + (size_t)ra * lda2 + kg * 8;
        sB[i]  = Bt + (size_t)(col0 + rs) * K + kg * 8;
    }

    f32x4 acc[4][4];
#pragma unroll
    for (int i = 0; i < 4; ++i)
#pragma unroll
        for (int j = 0; j < 4; ++j) acc[i][j] = (f32x4){0.f, 0.f, 0.f, 0.f};

    for (int kc = 0; kc < K; kc += 64) {
#pragma unroll
        for (int i = 0; i < 4; ++i) {
            const ushort* as = (SPLITA && kc < 128) ? (sA1[i] + kc) : (sA2[i] + (SPLITA ? kc - 128 : kc));
            ld16(as, &As[(wave * 4 + i) * 512]);
            ld16(sB[i] + kc, &Bs[(wave * 4 + i) * 512]);
        }
        __syncthreads();
#pragma unroll
        for (int h = 0; h < 2; ++h) {
            f16x8 af[4], bf[4];
#pragma unroll
            for (int i = 0; i < 4; ++i) {
                int r = wm * 64 + i * 16 + l16;
                af[i] = *(const f16x8*)&As[r * 64 + (((h * 4 + quad) ^ (r & 7)) * 8)];
                int c = wn * 64 + i * 16 + l16;
                bf[i] = *(const f16x8*)&Bs[c * 64 + (((h * 4 + quad) ^ (c & 7)) * 8)];
            }
#pragma unroll
            for (int i = 0; i < 4; ++i)
#pragma unroll
                for (int j = 0; j < 4; ++j)
                    acc[i][j] = __builtin_amdgcn_mfma_f32_16x16x32_f16(af[i], bf[j], acc[i][j], 0, 0, 0);
        }
        __syncthreads();
    }

#pragma unroll
    for (int i = 0; i < 4; ++i) {
        int gr0 = row0 + wm * 64 + i * 16 + quad * 4;
#pragma unroll
        for (int r = 0; r < 4; ++r) {
            int grow = gr0 + r;
            if (grow >= M) continue;
#pragma unroll
            for (int j = 0; j < 4; ++j) {
                int gcol = col0 + wn * 64 + j * 16 + l16;
                float v = acc[i][j][r] + bias[gcol];
                if (RELU) v = fmaxf(v, 0.f);
                if (F16OUT) ((ushort*)Cout)[(size_t)grow * ldc + gcol] = f2h(v);
                else        ((float*)Cout)[(size_t)grow * ldc + gcol] = v;
            }
        }
    }
}

// ------------------------------------------------ fp16 MFMA GEMM + fused row LayerNorm
template<bool F16OUT>
__global__ __launch_bounds__(256, 3)
void mfma_gemm_ln(const ushort* __restrict__ A, int lda, int M,
                  const ushort* __restrict__ Bt, int K,
                  const float* __restrict__ bias, const float* __restrict__ lng,
                  const float* __restrict__ lnb, void* __restrict__ Cout) {
    __shared__ ushort As[128 * 64];
    __shared__ ushort Bs[128 * 64];
    __shared__ float rsum[2][128];
    __shared__ float rsq[2][128];
    const int tid = threadIdx.x;
    const int lane = tid & 63;
    const int wave = tid >> 6;
    const int wm = wave & 1, wn = wave >> 1;
    const int quad = lane >> 4, l16 = lane & 15;
    const int row0 = blockIdx.y * 128;

    const ushort* sA[4];
    const ushort* sB[4];
#pragma unroll
    for (int i = 0; i < 4; ++i) {
        int rs = (wave * 4 + i) * 8 + (lane >> 3);
        int kg = (lane & 7) ^ (rs & 7);
        int ra = row0 + rs; if (ra >= M) ra = M - 1;
        sA[i] = A + (size_t)ra * lda + kg * 8;
        sB[i] = Bt + (size_t)rs * K + kg * 8;
    }

    f32x4 acc[4][4];
#pragma unroll
    for (int i = 0; i < 4; ++i)
#pragma unroll
        for (int j = 0; j < 4; ++j) acc[i][j] = (f32x4){0.f, 0.f, 0.f, 0.f};

    for (int kc = 0; kc < K; kc += 64) {
#pragma unroll
        for (int i = 0; i < 4; ++i) {
            ld16(sA[i] + kc, &As[(wave * 4 + i) * 512]);
            ld16(sB[i] + kc, &Bs[(wave * 4 + i) * 512]);
        }
        __syncthreads();
#pragma unroll
        for (int h = 0; h < 2; ++h) {
            f16x8 af[4], bf[4];
#pragma unroll
            for (int i = 0; i < 4; ++i) {
                int r = wm * 64 + i * 16 + l16;
                af[i] = *(const f16x8*)&As[r * 64 + (((h * 4 + quad) ^ (r & 7)) * 8)];
                int c = wn * 64 + i * 16 + l16;
                bf[i] = *(const f16x8*)&Bs[c * 64 + (((h * 4 + quad) ^ (c & 7)) * 8)];
            }
#pragma unroll
            for (int i = 0; i < 4; ++i)
#pragma unroll
                for (int j = 0; j < 4; ++j)
                    acc[i][j] = __builtin_amdgcn_mfma_f32_16x16x32_f16(af[i], bf[j], acc[i][j], 0, 0, 0);
        }
        __syncthreads();
    }

#pragma unroll
    for (int i = 0; i < 4; ++i) {
#pragma unroll
        for (int r = 0; r < 4; ++r) {
            float s = 0.f, q = 0.f;
#pragma unroll
            for (int j = 0; j < 4; ++j) {
                float v = acc[i][j][r] + bias[wn * 64 + j * 16 + l16];
                s += v; q += v * v;
            }
            s += __shfl_xor(s, 1); q += __shfl_xor(q, 1);
            s += __shfl_xor(s, 2); q += __shfl_xor(q, 2);
            s += __shfl_xor(s, 4); q += __shfl_xor(q, 4);
            s += __shfl_xor(s, 8); q += __shfl_xor(q, 8);
            if (l16 == 0) {
                int row = wm * 64 + i * 16 + quad * 4 + r;
                rsum[wn][row] = s;
                rsq[wn][row] = q;
            }
        }
    }
    __syncthreads();

#pragma unroll
    for (int i = 0; i < 4; ++i) {
#pragma unroll
        for (int r = 0; r < 4; ++r) {
            int row = wm * 64 + i * 16 + quad * 4 + r;
            int grow = row0 + row;
            if (grow >= M) continue;
            float tot = rsum[0][row] + rsum[1][row];
            float tq  = rsq[0][row] + rsq[1][row];
            float mu = tot * (1.f / 128.f);
            float var = tq * (1.f / 128.f) - mu * mu;
            float rstd = rsqrtf(var + 1e-5f);
#pragma unroll
            for (int j = 0; j < 4; ++j) {
                int gcol = wn * 64 + j * 16 + l16;
                float v = acc[i][j][r] + bias[gcol];
                float o = lng[gcol] * (v - mu) * rstd + lnb[gcol];
                if (F16OUT) ((ushort*)Cout)[(size_t)grow * 128 + gcol] = f2h(o);
                else        ((float*)Cout)[(size_t)grow * 128 + gcol] = o;
            }
        }
    }
}

// --------------------------------------------------------------- attention
// round-4 structure (separate K/V ushort2 loads, 2-edge unroll) + v_dot2_f32_f16 scores.
__global__ __launch_bounds__(256)
void attn_kernel(const ushort* __restrict__ C, const int* __restrict__ ssrc,
                 const int* __restrict__ estart, const int* __restrict__ ecnt,
                 ushort* __restrict__ attnhf) {
    int n = (blockIdx.x * 256 + threadIdx.x) >> 6;
    if (n >= N_NODES) return;
    int lane = threadIdx.x & 63;
    h16x2 qh = *(const h16x2*)&C[(size_t)n * 384 + 2 * lane];
    int e0 = estart[n], e1 = e0 + ecnt[n];
    float wvx = 0.f, wvy = 0.f, z = 0.f;
    int e = e0;
    for (; e + 2 <= e1; e += 2) {
        int s0 = ssrc[e], s1 = ssrc[e + 1];
        h16x2 k0 = *(const h16x2*)&C[(size_t)s0 * 384 + 128 + 2 * lane];
        h16x2 k1 = *(const h16x2*)&C[(size_t)s1 * 384 + 128 + 2 * lane];
        h16x2 v0 = *(const h16x2*)&C[(size_t)s0 * 384 + 256 + 2 * lane];
        h16x2 v1 = *(const h16x2*)&C[(size_t)s1 * 384 + 256 + 2 * lane];
        float d0 = __builtin_amdgcn_fdot2(k0, qh, 0.f, false);
        float d1 = __builtin_amdgcn_fdot2(k1, qh, 0.f, false);
        d0 += __shfl_xor(d0, 1); d1 += __shfl_xor(d1, 1);
        d0 += __shfl_xor(d0, 2); d1 += __shfl_xor(d1, 2);
        d0 += __shfl_xor(d0, 4); d1 += __shfl_xor(d1, 4);
        float sc0 = __expf(fminf(fmaxf(d0 * 0.25f, -10.f), 10.f));
        float sc1 = __expf(fminf(fmaxf(d1 * 0.25f, -10.f), 10.f));
        wvx += sc0 * (float)v0.x + sc1 * (float)v1.x;
        wvy += sc0 * (float)v0.y + sc1 * (float)v1.y;
        z += sc0 + sc1;
    }
    if (e < e1) {
        int s0 = ssrc[e];
        h16x2 k0 = *(const h16x2*)&C[(size_t)s0 * 384 + 128 + 2 * lane];
        h16x2 v0 = *(const h16x2*)&C[(size_t)s0 * 384 + 256 + 2 * lane];
        float d0 = __builtin_amdgcn_fdot2(k0, qh, 0.f, false);
        d0 += __shfl_xor(d0, 1);
        d0 += __shfl_xor(d0, 2);
        d0 += __shfl_xor(d0, 4);
        float sc0 = __expf(fminf(fmaxf(d0 * 0.25f, -10.f), 10.f));
        wvx += sc0 * (float)v0.x;
        wvy += sc0 * (float)v0.y;
        z += sc0;
    }
    float inv = 1.f / (z + 1e-6f);
    ushort2 o;
    o.x = f2h(wvx * inv);
    o.y = f2h(wvy * inv);
    *(ushort2*)&attnhf[(size_t)n * D + 2 * lane] = o;
}

// ------------------------------------------------------------------ launch
extern "C" void kernel_launch(void* const* d_in, const int* in_sizes, int n_in,
                              void* d_out, int out_size, void* d_ws, size_t ws_size,
                              hipStream_t stream) {
    (void)in_sizes; (void)n_in; (void)out_size;
    const float* h     = (const float*)d_in[0];
    const int*   src   = (const int*)d_in[1];
    const int*   dst   = (const int*)d_in[2];
    const int*   ety   = (const int*)d_in[3];
    const int*   seg   = (const int*)d_in[4];
    const float* coeffs[3] = {(const float*)d_in[6],  (const float*)d_in[10], (const float*)d_in[14]};
    const float* bases [3] = {(const float*)d_in[7],  (const float*)d_in[11], (const float*)d_in[15]};
    const float* loops [3] = {(const float*)d_in[8],  (const float*)d_in[12], (const float*)d_in[16]};
    const float* pbias [3] = {(const float*)d_in[9],  (const float*)d_in[13], (const float*)d_in[17]};
    const float* o_w   = (const float*)d_in[18];
    const float* o_b   = (const float*)d_in[19];
    const float* gn1_w = (const float*)d_in[20];
    const float* gn1_b = (const float*)d_in[21];
    const float* gn1_ms= (const float*)d_in[22];
    const float* gn2_w = (const float*)d_in[23];
    const float* gn2_b = (const float*)d_in[24];
    const float* gn2_ms= (const float*)d_in[25];
    const float* ln1_g = (const float*)d_in[26];
    const float* ln1_b = (const float*)d_in[27];
    const float* ln2_g = (const float*)d_in[28];
    const float* ln2_b = (const float*)d_in[29];
    const float* ffn1_w= (const float*)d_in[30];
    const float* ffn1_b= (const float*)d_in[31];
    const float* ffn2_w= (const float*)d_in[32];
    const float* ffn2_b= (const float*)d_in[33];

    char* p = (char*)d_ws;
    auto take = [&](size_t bytes) { char* r = p; p += (bytes + 255) & ~(size_t)255; return r; };
    int*    ecnt   = (int*)take((size_t)N_NODES * 4);
    int*    ecur   = (int*)take((size_t)N_NODES * 4);   // adjacent to ecnt -> single memset
    int*    estart = (int*)take((size_t)N_NODES * 4);
    int*    bsum   = (int*)take(512);
    int*    ssrc   = (int*)take((size_t)N_EDGES * 4);
    int*    setp   = (int*)take((size_t)N_EDGES * 4);
    float*  gsum   = (float*)take((size_t)NG * D * 4 * 2);
    float*  gsumsq = gsum + NG * D;
    float*  gsc    = (float*)take((size_t)NG * D * 4);
    float*  goff   = (float*)take((size_t)NG * D * 4);
    ushort* Btqkv  = (ushort*)take((size_t)384 * 1280 * 2);
    float*  biasq  = (float*)take(384 * 4);
    ushort* Bto    = (ushort*)take((size_t)128 * 128 * 2);
    ushort* Btf1   = (ushort*)take((size_t)256 * 128 * 2);
    ushort* Btf2   = (ushort*)take((size_t)128 * 256 * 2);
    ushort* hnhf   = (ushort*)take((size_t)N_NODES * D * 2);     // 25.6 MB
    ushort* attnhf = (ushort*)take((size_t)N_NODES * D * 2);     // 25.6 MB
    ushort* h1hf   = (ushort*)take((size_t)N_NODES * D * 2);     // 25.6 MB
    ushort* Cqkv   = (ushort*)take((size_t)N_NODES * 384 * 2);   // 76.8 MB
    size_t used = (size_t)(p - (char*)d_ws);
    size_t avail = (ws_size > used) ? ws_size - used : 0;
    int NC = 1;
    if (avail < (size_t)N_NODES * 1152 * 2) NC = 4;
    if (NC == 4 && avail < ((size_t)(N_NODES / 4 + 1) * 1152 * 2)) NC = 8;
    ushort* Ab = (ushort*)p;
    const int chunk = (N_NODES + NC - 1) / NC;

    // dead-buffer aliases: Cqkv dead after attention; holds gn2hf (25.6) + ffn1hf (51.2)
    ushort* gn2hf  = Cqkv;
    ushort* ffn1hf = (ushort*)((char*)Cqkv + 25600000);

    const int EB = (N_EDGES + 255) / 256;
    const int SB = (N_NODES + 1023) / 1024;
    const int WB = (N_NODES * 64 + 255) / 256;
    const int GB = (N_NODES + 127) / 128;
    const int RB = (N_NODES + 127) / 128;

    // ---- sort edges by dst
    hipMemsetAsync(ecnt, 0, (size_t)((char*)(estart) - (char*)ecnt), stream);  // ecnt + ecur
    hist_kernel<<<EB, 256, 0, stream>>>(dst, ecnt);
    scan1_kernel<<<SB, 1024, 0, stream>>>(ecnt, estart, bsum, N_NODES);
    scan2_kernel<<<1, 128, 0, stream>>>(bsum, SB);
    scan3_kernel<<<SB, 1024, 0, stream>>>(estart, bsum, N_NODES);
    scatter_kernel<<<EB, 256, 0, stream>>>(src, dst, ety, estart, ecur, ssrc, setp);

    // ---- weights (2 dispatches total)
    build_bt_qkv3<<<dim3(640, 3), 256, 0, stream>>>(
        coeffs[0], coeffs[1], coeffs[2], bases[0], bases[1], bases[2],
        loops[0], loops[1], loops[2], pbias[0], pbias[1], pbias[2], Btqkv, biasq);
    transpose_cast3<<<320, 256, 0, stream>>>(o_w, Bto, ffn1_w, Btf1, ffn2_w, Btf2);

    // ---- graph norm 1 -> hnhf (fp16)
    hipMemsetAsync(gsum, 0, (size_t)NG * D * 8, stream);
    gn_stats<<<GB, 256, 0, stream>>>(h, seg, gsum, gsumsq);
    gn_final<<<NG, 128, 0, stream>>>(gsum, gsumsq, seg, gn1_w, gn1_b, gn1_ms, gsc, goff);
    gn_apply<<<WB, 256, 0, stream>>>(h, seg, gsc, goff, hnhf);

    // ---- QKV: S-pass + split-A MFMA GEMM per chunk -> Cqkv (fp16)
    for (int c = 0; c < NC; ++c) {
        int c0 = c * chunk;
        int c1 = min(N_NODES, c0 + chunk);
        int rows = c1 - c0;
        if (rows <= 0) break;
        s_pass<<<(rows + 3) / 4, 256, 0, stream>>>(hnhf, ssrc, setp, estart, ecnt, Ab, c0, c1);
        mfma_gemm<true, true, true><<<dim3(3, (rows + 127) / 128), 256, 0, stream>>>(
            hnhf + (size_t)c0 * 128, Ab, 1152, rows, Btqkv, 1280, biasq,
            Cqkv + (size_t)c0 * 384, 384);
    }

    // ---- attention -> attnhf (fp16); Cqkv dead after this
    attn_kernel<<<WB, 256, 0, stream>>>(Cqkv, ssrc, estart, ecnt, attnhf);

    // ---- output projection + fused ln1 -> h1hf (fp16)
    mfma_gemm_ln<true><<<dim3(1, RB), 256, 0, stream>>>(
        attnhf, 128, N_NODES, Bto, 128, o_b, ln1_g, ln1_b, h1hf);

    // ---- graph norm 2 (fp16 path) -> gn2hf
    hipMemsetAsync(gsum, 0, (size_t)NG * D * 8, stream);
    gn_stats_h<<<GB, 256, 0, stream>>>(h1hf, seg, gsum, gsumsq);
    gn_final<<<NG, 128, 0, stream>>>(gsum, gsumsq, seg, gn2_w, gn2_b, gn2_ms, gsc, goff);
    gn_apply_h<<<WB, 256, 0, stream>>>(h1hf, seg, gsc, goff, gn2hf);

    // ---- FFN: ffn1 (relu, fp16) then ffn2 + fused ln2 -> d_out (fp32)
    mfma_gemm<false, true, true><<<dim3(2, RB), 256, 0, stream>>>(
        nullptr, gn2hf, 128, N_NODES, Btf1, 128, ffn1_b, ffn1hf, 256);
    mfma_gemm_ln<false><<<dim3(1, RB), 256, 0, stream>>>(
        ffn1hf, 256, N_NODES, Btf2, 256, ffn2_b, ln2_g, ln2_b, (float*)d_out);
}